// Round 8
// baseline (545.423 us; speedup 1.0000x reference)
//
#include <hip/hip_runtime.h>

// ---------------------------------------------------------------------------
// BiLstmCrf: bidirectional lattice-LSTM + CRF NLL -> one scalar.
//
//   1. gemm_char : Xg(f+r) AND Xl(f+r) from one staged char-emb gather
//   2. gemm_pair : Wg(f+r)
//   3. lattice_kernel : 32 WGs (one per (batch,dir)), 512 thr (8 waves).
//        ALL matvecs on the MFMA pipe (mfma_f32_16x16x32_f16, broadcast-A);
//        weights resident in VGPRs as B-fragments (~128 VGPR). h history
//        (f16) + c history (f32) in LDS. 1 lgkm-only barrier per eventless
//        step; straight-line E<=2 event path. [UNCHANGED from best round]
//   4. gemm_pair : logits = feats @ dense_W + dense_b
//   5. crf_kernel : ONE block, 512 thr; one 32-lane half per batch; alpha
//        broadcast via intra-32 shuffles (no __syncthreads in the t-loop);
//        finalize fused into the block tail.
// ---------------------------------------------------------------------------

typedef _Float16 f16x8 __attribute__((ext_vector_type(8)));
typedef float    f32x4 __attribute__((ext_vector_type(4)));

__device__ __forceinline__ float sigm(float x) { return 1.f / (1.f + __expf(-x)); }
__device__ __forceinline__ float tanh_fast(float x) {
    return 1.f - 2.f / (__expf(2.f * x) + 1.f);
}
// lgkm-only barrier: LDS ops drained, vmem loads stay outstanding.
__device__ __forceinline__ void bar_lgkm() {
    asm volatile("s_waitcnt lgkmcnt(0)\n\ts_barrier" ::: "memory");
}

__device__ __forceinline__ f32x4 mfma16(f16x8 a, f16x8 b, f32x4 c) {
    return __builtin_amdgcn_mfma_f32_16x16x32_f16(a, b, c, 0, 0, 0);
}

// ---------------------------------------------------------------------------
// Combined char gemm: stage 8 rows of char_emb once, produce Xg (J=512) and
// Xl (J=128). blockIdx.y = direction (y=1 uses reversed row order + r_* W).
// ---------------------------------------------------------------------------
__global__ __launch_bounds__(256)
void gemm_char(const float* __restrict__ emb, const int* __restrict__ idx,
               const float* __restrict__ Wg0, const float* __restrict__ Wg1,
               const float* __restrict__ bg0, const float* __restrict__ bg1,
               const float* __restrict__ Wl0, const float* __restrict__ Wl1,
               const float* __restrict__ bl0, const float* __restrict__ bl1,
               float* __restrict__ outg, float* __restrict__ outl)
{
    constexpr int K = 128, RPB = 8, BLK = 256;
    const int y = blockIdx.y;
    const float* __restrict__ Wg = y ? Wg1 : Wg0;
    const float* __restrict__ bg = y ? bg1 : bg0;
    const float* __restrict__ Wl = y ? Wl1 : Wl0;
    const float* __restrict__ bl = y ? bl1 : bl0;
    float* __restrict__ og = outg + (size_t)y * 2048 * 512;
    float* __restrict__ ol = outl + (size_t)y * 2048 * 128;

    __shared__ __align__(16) float xs[RPB * K];
    __shared__ const float* srcs[RPB];
    const int tid = threadIdx.x;
    const int r0 = blockIdx.x * RPB;
    if (tid < RPB) {
        const int row = r0 + tid;
        const int bb = row >> 7, tt = row & 127;
        const int ts = y ? (127 - tt) : tt;
        srcs[tid] = emb + (size_t)idx[bb * 128 + ts] * K;
    }
    __syncthreads();
    constexpr int NQ = RPB * K / 4;
    for (int q = tid; q < NQ; q += BLK) {
        const int rr = q / (K / 4), qq = q - rr * (K / 4);
        ((float4*)xs)[q] = ((const float4*)srcs[rr])[qq];
    }
    __syncthreads();

    // ---- phase 1: J = 512 (Xg) -------------------------------------------
    {
        constexpr int NJ4 = 128, RT = BLK / NJ4, RPT = RPB / RT;  // 2, 4
        const int jq = tid % NJ4;
        const int rg = tid / NJ4;
        float4 acc[RPT];
#pragma unroll
        for (int r = 0; r < RPT; ++r) acc[r] = make_float4(0.f, 0.f, 0.f, 0.f);
        const float4* __restrict__ W4 = (const float4*)Wg;
#pragma unroll 4
        for (int k = 0; k < K; ++k) {
            const float4 wv = W4[(size_t)k * NJ4 + jq];
#pragma unroll
            for (int r = 0; r < RPT; ++r) {
                const float xv = xs[(rg * RPT + r) * K + k];
                acc[r].x = fmaf(xv, wv.x, acc[r].x);
                acc[r].y = fmaf(xv, wv.y, acc[r].y);
                acc[r].z = fmaf(xv, wv.z, acc[r].z);
                acc[r].w = fmaf(xv, wv.w, acc[r].w);
            }
        }
        const float4 bv = ((const float4*)bg)[jq];
#pragma unroll
        for (int r = 0; r < RPT; ++r) {
            const int row = r0 + rg * RPT + r;
            ((float4*)og)[(size_t)row * NJ4 + jq] =
                make_float4(acc[r].x + bv.x, acc[r].y + bv.y,
                            acc[r].z + bv.z, acc[r].w + bv.w);
        }
    }
    // ---- phase 2: J = 128 (Xl), xs unchanged -----------------------------
    {
        constexpr int NJ4 = 32, RT = BLK / NJ4;                   // 8
        const int jq = tid % NJ4;
        const int rg = tid / NJ4;                                 // 0..7 = row
        float4 acc = make_float4(0.f, 0.f, 0.f, 0.f);
        const float4* __restrict__ W4 = (const float4*)Wl;
#pragma unroll 4
        for (int k = 0; k < K; ++k) {
            const float4 wv = W4[(size_t)k * NJ4 + jq];
            const float xv = xs[rg * K + k];
            acc.x = fmaf(xv, wv.x, acc.x);
            acc.y = fmaf(xv, wv.y, acc.y);
            acc.z = fmaf(xv, wv.z, acc.z);
            acc.w = fmaf(xv, wv.w, acc.w);
        }
        const float4 bv = ((const float4*)bl)[jq];
        const int row = r0 + rg;
        (void)RT;
        ((float4*)ol)[(size_t)row * NJ4 + jq] =
            make_float4(acc.x + bv.x, acc.y + bv.y, acc.z + bv.z, acc.w + bv.w);
    }
}

// ---------------------------------------------------------------------------
// Generic gemm (used for Wg and logits). Same as previous rounds.
// ---------------------------------------------------------------------------
template <int K, int J, int RPB, int BLK>
__global__ __launch_bounds__(BLK)
void gemm_pair(const float* __restrict__ emb, const int* __restrict__ idx,
               const float* __restrict__ W0, const float* __restrict__ W1,
               const float* __restrict__ b0, const float* __restrict__ b1,
               float* __restrict__ out, int rowsTotal, int Sdim, int revmode)
{
    constexpr int NJ4 = J / 4;
    constexpr int RT  = BLK / NJ4;
    constexpr int RPT = RPB / RT;
    static_assert(BLK % NJ4 == 0 && RPB % RT == 0, "layout");
    const int y = blockIdx.y;
    const float* __restrict__ W    = y ? W1 : W0;
    const float* __restrict__ bias = y ? b1 : b0;
    float* __restrict__ outp = out + (size_t)y * rowsTotal * J;
    const int rev = (revmode && y) ? 1 : 0;

    __shared__ __align__(16) float xs[RPB * K];
    __shared__ const float* srcs[RPB];
    const int tid = threadIdx.x;
    const int r0 = blockIdx.x * RPB;
    if (tid < RPB) {
        const int row = r0 + tid;
        const float* s = nullptr;
        if (row < rowsTotal) {
            if (idx) {
                const int bb = row / Sdim, tt = row - bb * Sdim;
                const int ts = rev ? (Sdim - 1 - tt) : tt;
                s = emb + (size_t)idx[bb * Sdim + ts] * K;
            } else {
                s = emb + (size_t)row * K;
            }
        }
        srcs[tid] = s;
    }
    __syncthreads();
    constexpr int NQ = RPB * K / 4;
    for (int q = tid; q < NQ; q += BLK) {
        const int rr = q / (K / 4), qq = q - rr * (K / 4);
        const float4* s = (const float4*)srcs[rr];
        ((float4*)xs)[q] = s ? s[qq] : make_float4(0.f, 0.f, 0.f, 0.f);
    }
    __syncthreads();

    const int jq = tid % NJ4;
    const int rg = tid / NJ4;
    float4 acc[RPT];
#pragma unroll
    for (int r = 0; r < RPT; ++r) acc[r] = make_float4(0.f, 0.f, 0.f, 0.f);
    const float4* __restrict__ W4 = (const float4*)W;
#pragma unroll 4
    for (int k = 0; k < K; ++k) {
        const float4 wv = W4[(size_t)k * NJ4 + jq];
#pragma unroll
        for (int r = 0; r < RPT; ++r) {
            const float xv = xs[(rg * RPT + r) * K + k];
            acc[r].x = fmaf(xv, wv.x, acc[r].x);
            acc[r].y = fmaf(xv, wv.y, acc[r].y);
            acc[r].z = fmaf(xv, wv.z, acc[r].z);
            acc[r].w = fmaf(xv, wv.w, acc[r].w);
        }
    }
    const float4 bv = ((const float4*)bias)[jq];
#pragma unroll
    for (int r = 0; r < RPT; ++r) {
        const int row = r0 + rg * RPT + r;
        if (row < rowsTotal)
            ((float4*)outp)[(size_t)row * NJ4 + jq] =
                make_float4(acc[r].x + bv.x, acc[r].y + bv.y,
                            acc[r].z + bv.z, acc[r].w + bv.w);
    }
}

// ---------------------------------------------------------------------------
// Lattice scan. One WG per (batch,dir). MFMA layout: wave wid owns columns
// jm = 16*wid + (lane&15). Dynamic LDS: hh (f16, 129*128) + ch (f32, 129*128).
// [UNCHANGED from Round 7 — proven 184 us]
// ---------------------------------------------------------------------------
#define HH_BYTES (129 * 128 * 2)
#define CH_BYTES (129 * 128 * 4)
#define LAT_DYN_SMEM (HH_BYTES + CH_BYTES)

__global__ __launch_bounds__(512, 2)
void lattice_kernel(const float* __restrict__ Xg,    // [2][B*S][512]
                    const float* __restrict__ Xl,    // [2][B*S][128]
                    const float* __restrict__ Wgp,   // [2][B*N][384]
                    const float* __restrict__ Wch_f, const float* __restrict__ Wch_r,
                    const float* __restrict__ Wwh_f, const float* __restrict__ Wwh_r,
                    const float* __restrict__ Wlc_f, const float* __restrict__ Wlc_r,
                    const int* __restrict__ word_begin, const int* __restrict__ word_len,
                    const int* __restrict__ seqlen,
                    float* __restrict__ feats)       // [B*S][256]
{
    extern __shared__ __align__(16) char dyn_smem[];
    _Float16* hh = (_Float16*)dyn_smem;                    // [129][128]
    float*    ch = (float*)(dyn_smem + HH_BYTES);          // [129][128]

    const int bdid = blockIdx.x;
    const int b = bdid >> 1, dir = bdid & 1;
    const int tid = threadIdx.x;
    const int wid = tid >> 6;     // wave 0..7
    const int ln  = tid & 63;     // lane
    const int lg  = ln >> 4;      // k-group 0..3 within MFMA operand
    const int jm  = wid * 16 + (ln & 15);   // owned column 0..127

    const float* Wch = dir ? Wch_r : Wch_f;
    const float* Wwh = dir ? Wwh_r : Wwh_f;
    const float* Wlc = dir ? Wlc_r : Wlc_f;

    // ---- weights -> VGPRs as MFMA B-fragments -----------------------------
    f16x8 Bc[4][4];   // [gate][kt]
#pragma unroll
    for (int g = 0; g < 4; ++g)
#pragma unroll
        for (int kt = 0; kt < 4; ++kt) {
            f16x8 v;
#pragma unroll
            for (int i = 0; i < 8; ++i)
                v[i] = (_Float16)Wch[(size_t)(kt * 32 + lg * 8 + i) * 512 + (g * 128 + jm)];
            Bc[g][kt] = v;
        }
    f16x8 Bw[3][4];   // [part][kt]
#pragma unroll
    for (int p = 0; p < 3; ++p)
#pragma unroll
        for (int kt = 0; kt < 4; ++kt) {
            f16x8 v;
#pragma unroll
            for (int i = 0; i < 8; ++i)
                v[i] = (_Float16)Wwh[(size_t)(kt * 32 + lg * 8 + i) * 384 + (p * 128 + jm)];
            Bw[p][kt] = v;
        }
    f16x8 Bl[4];      // [kt]
#pragma unroll
    for (int kt = 0; kt < 4; ++kt) {
        f16x8 v;
#pragma unroll
        for (int i = 0; i < 8; ++i)
            v[i] = (_Float16)Wlc[(size_t)(kt * 32 + lg * 8 + i) * 128 + jm];
        Bl[kt] = v;
    }

    // ---- static LDS --------------------------------------------------------
    __shared__ __align__(16) _Float16 cw2s[2][2][128];   // [chunk-parity][slot][col]
    __shared__ int ev_start[129];
    __shared__ int cnts[128];
    __shared__ int fills[128];
    __shared__ short ev_word[64];
    __shared__ short wbeg_s[64];

    const int sl = seqlen[b];

    // ---- event schedule ----------------------------------------------------
    if (tid < 128) { cnts[tid] = 0; fills[tid] = 0; }
    __syncthreads();
    int myvalid = 0, myed = 0;
    if (tid < 64) {
        const int bg = word_begin[b * 64 + tid];
        const int lnw = word_len[b * 64 + tid];
        int ef = bg + lnw; if (ef > 127) ef = 127;
        myvalid = (ef < sl);
        const int bd_ = dir ? (127 - ef) : bg;
        const int ed_ = dir ? (127 - bg) : ef;
        wbeg_s[tid] = (short)bd_;
        myed = ed_;
        if (myvalid) atomicAdd(&cnts[ed_], 1);
    }
    __syncthreads();
    if (tid == 0) {
        int run = 0; ev_start[0] = 0;
        for (int t = 0; t < 128; ++t) { run += cnts[t]; ev_start[t + 1] = run; }
    }
    __syncthreads();
    if (tid < 64 && myvalid) {
        const int pos = atomicAdd(&fills[myed], 1);
        ev_word[ev_start[myed] + pos] = (short)tid;
    }
    if (tid < 128) { hh[tid] = (_Float16)0.f; ch[tid] = 0.f; }   // slot 0
    __syncthreads();

    const float* Xg_b = Xg + ((size_t)dir * 2048 + (size_t)b * 128) * 512;
    const float* Xl_b = Xl + ((size_t)dir * 2048 + (size_t)b * 128) * 128;
    const float* Wg_b = Wgp + ((size_t)dir * 1024 + (size_t)b * 64) * 384;

    float h_reg = 0.f, c_reg = 0.f;

    // ---- pipeline registers: step-t event data prefetched at step t-1 ------
    int   curE, cur_ec0;
    int   cur_bgs[2] = {0, 0};
    float cur_wgp[2][3] = {};
    float xg_cur[4];
    {
        curE = ev_start[1];                // e0 = 0
        cur_ec0 = curE < 2 ? curE : 2;
#pragma unroll
        for (int s = 0; s < 2; ++s)
            if (s < cur_ec0) {
                const int wd = __builtin_amdgcn_readfirstlane((int)ev_word[s]);
                cur_bgs[s] = __builtin_amdgcn_readfirstlane((int)wbeg_s[wd]);
                const float* wgr = Wg_b + (size_t)wd * 384;
                cur_wgp[s][0] = wgr[jm];
                cur_wgp[s][1] = wgr[128 + jm];
                cur_wgp[s][2] = wgr[256 + jm];
            }
#pragma unroll
        for (int g = 0; g < 4; ++g) xg_cur[g] = Xg_b[g * 128 + jm];
    }

    for (int t = 0; t < 128; ++t) {
        // ---- A-fragments for char matvec: issue LDS reads first -----------
        f16x8 A[4];
#pragma unroll
        for (int kt = 0; kt < 4; ++kt)
            A[kt] = ((const f16x8*)hh)[t * 16 + kt * 4 + lg];

        // ---- Xl for current step (L2-resident; consumed after barrier) ----
        float xl = 0.f;
        if (curE > 0) xl = Xl_b[(size_t)t * 128 + jm];

        // ---- prefetch step t+1 (in flight across lgkm barriers) -----------
        int   nxtE = 0, nxt_ec0 = 0;
        int   nxt_bgs[2] = {0, 0};
        float nxt_wgp[2][3] = {};
        float xg_nxt[4] = {0.f, 0.f, 0.f, 0.f};
        if (t < 127) {
            const int e0n = ev_start[t + 1];
            nxtE = ev_start[t + 2] - e0n;
            nxt_ec0 = nxtE < 2 ? nxtE : 2;
#pragma unroll
            for (int s = 0; s < 2; ++s)
                if (s < nxt_ec0) {
                    const int wd = __builtin_amdgcn_readfirstlane((int)ev_word[e0n + s]);
                    nxt_bgs[s] = __builtin_amdgcn_readfirstlane((int)wbeg_s[wd]);
                    const float* wgr = Wg_b + (size_t)wd * 384;
                    nxt_wgp[s][0] = wgr[jm];
                    nxt_wgp[s][1] = wgr[128 + jm];
                    nxt_wgp[s][2] = wgr[256 + jm];
                }
#pragma unroll
            for (int g = 0; g < 4; ++g)
                xg_nxt[g] = Xg_b[(size_t)(t + 1) * 512 + g * 128 + jm];
        }

        // ---- char matvec: 16 MFMA, broadcast-A = h[t] ---------------------
        f32x4 d[4];
#pragma unroll
        for (int g = 0; g < 4; ++g) d[g] = (f32x4){0.f, 0.f, 0.f, 0.f};
#pragma unroll
        for (int kt = 0; kt < 4; ++kt)
#pragma unroll
            for (int g = 0; g < 4; ++g)
                d[g] = mfma16(A[kt], Bc[g][kt], d[g]);

        const float gi = sigm(d[0][0] + xg_cur[0]);
        const float gf = sigm(d[1][0] + xg_cur[1]);
        const float go = sigm(d[2][0] + xg_cur[2]);
        const float gg = tanh_fast(d[3][0] + xg_cur[3]);

        float accn = 0.f, accd = 0.f;
        if (curE > 0) {
            const int e0 = ev_start[t];
            // ---- first chunk (covers E<=2, the dominant case) -------------
            float cwreg[2] = {0.f, 0.f};
#pragma unroll
            for (int s = 0; s < 2; ++s)
                if (s < cur_ec0) {
                    f16x8 Ab[4];
#pragma unroll
                    for (int kt = 0; kt < 4; ++kt)
                        Ab[kt] = ((const f16x8*)hh)[cur_bgs[s] * 16 + kt * 4 + lg];
                    f32x4 ep[3];
#pragma unroll
                    for (int p = 0; p < 3; ++p) ep[p] = (f32x4){0.f, 0.f, 0.f, 0.f};
#pragma unroll
                    for (int kt = 0; kt < 4; ++kt)
#pragma unroll
                        for (int p = 0; p < 3; ++p)
                            ep[p] = mfma16(Ab[kt], Bw[p][kt], ep[p]);
                    const float wi = cur_wgp[s][0] + ep[0][0];
                    const float wf = cur_wgp[s][1] + ep[1][0];
                    const float wv = cur_wgp[s][2] + ep[2][0];
                    const float cb = ch[(size_t)cur_bgs[s] * 128 + jm];
                    const float cwv = sigm(wf) * cb + sigm(wi) * tanh_fast(wv);
                    cwreg[s] = cwv;
                    if (ln < 16) cw2s[0][s][jm] = (_Float16)cwv;
                }
            bar_lgkm();   // publish cw2s[0]
#pragma unroll
            for (int s = 0; s < 2; ++s)
                if (s < cur_ec0) {
                    f16x8 Ac[4];
#pragma unroll
                    for (int kt = 0; kt < 4; ++kt)
                        Ac[kt] = ((const f16x8*)(&cw2s[0][s][0]))[kt * 4 + lg];
                    f32x4 r = (f32x4){0.f, 0.f, 0.f, 0.f};
#pragma unroll
                    for (int kt = 0; kt < 4; ++kt)
                        r = mfma16(Ac[kt], Bl[kt], r);
                    const float lgv = sigm(xl + r[0]);
                    const float ew = __expf(lgv);
                    accn = fmaf(ew, cwreg[s], accn);
                    accd += ew;
                }
            // ---- rare tail: E > 2, simple sequential chunks ---------------
            for (int base2 = 2; base2 < curE; base2 += 2) {
                const int bb = (base2 >> 1) & 1;
                const int en = (curE - base2) < 2 ? (curE - base2) : 2;
                float cwr2[2] = {0.f, 0.f};
#pragma unroll
                for (int s = 0; s < 2; ++s)
                    if (s < en) {
                        const int wd = __builtin_amdgcn_readfirstlane((int)ev_word[e0 + base2 + s]);
                        const int bg2 = __builtin_amdgcn_readfirstlane((int)wbeg_s[wd]);
                        const float* wgr = Wg_b + (size_t)wd * 384;
                        const float wg0 = wgr[jm], wg1 = wgr[128 + jm], wg2 = wgr[256 + jm];
                        f16x8 Ab[4];
#pragma unroll
                        for (int kt = 0; kt < 4; ++kt)
                            Ab[kt] = ((const f16x8*)hh)[bg2 * 16 + kt * 4 + lg];
                        f32x4 ep[3];
#pragma unroll
                        for (int p = 0; p < 3; ++p) ep[p] = (f32x4){0.f, 0.f, 0.f, 0.f};
#pragma unroll
                        for (int kt = 0; kt < 4; ++kt)
#pragma unroll
                            for (int p = 0; p < 3; ++p)
                                ep[p] = mfma16(Ab[kt], Bw[p][kt], ep[p]);
                        const float wi = wg0 + ep[0][0];
                        const float wf = wg1 + ep[1][0];
                        const float wv = wg2 + ep[2][0];
                        const float cb = ch[(size_t)bg2 * 128 + jm];
                        const float cwv = sigm(wf) * cb + sigm(wi) * tanh_fast(wv);
                        cwr2[s] = cwv;
                        if (ln < 16) cw2s[bb][s][jm] = (_Float16)cwv;
                    }
                bar_lgkm();   // publish cw2s[bb]
#pragma unroll
                for (int s = 0; s < 2; ++s)
                    if (s < en) {
                        f16x8 Ac[4];
#pragma unroll
                        for (int kt = 0; kt < 4; ++kt)
                            Ac[kt] = ((const f16x8*)(&cw2s[bb][s][0]))[kt * 4 + lg];
                        f32x4 r = (f32x4){0.f, 0.f, 0.f, 0.f};
#pragma unroll
                        for (int kt = 0; kt < 4; ++kt)
                            r = mfma16(Ac[kt], Bl[kt], r);
                        const float lgv = sigm(xl + r[0]);
                        const float ew = __expf(lgv);
                        accn = fmaf(ew, cwr2[s], accn);
                        accd += ew;
                    }
            }
        }

        // ---- update (4 redundant lane-groups; group 0 writes) -------------
        float c_t;
        if (curE > 0) {
            const float ec = __expf(gi);
            c_t = (ec * gg + accn) / (ec + accd);
        } else {
            c_t = gf * c_reg + gi * gg;
        }
        const float h_t = go * tanh_fast(c_t);
        const bool v = dir ? (t >= 128 - sl) : (t < sl);
        const float hn = v ? h_t : h_reg;
        const float cn = v ? c_t : c_reg;
        h_reg = hn; c_reg = cn;
        if (ln < 16) {
            hh[(size_t)(t + 1) * 128 + jm] = (_Float16)hn;
            ch[(size_t)(t + 1) * 128 + jm] = cn;
        }

        // rotate pipeline
        curE = nxtE; cur_ec0 = nxt_ec0;
        cur_bgs[0] = nxt_bgs[0]; cur_bgs[1] = nxt_bgs[1];
#pragma unroll
        for (int s = 0; s < 2; ++s) {
            cur_wgp[s][0] = nxt_wgp[s][0];
            cur_wgp[s][1] = nxt_wgp[s][1];
            cur_wgp[s][2] = nxt_wgp[s][2];
        }
#pragma unroll
        for (int g = 0; g < 4; ++g) xg_cur[g] = xg_nxt[g];
        bar_lgkm();   // B: h/c (and cw2s buffers) visible for next step
    }

    // ---- epilogue: feats from LDS h history -------------------------------
    for (int i = tid; i < 128 * 128; i += 512) {
        const int t = i >> 7, j = i & 127;
        const bool v = dir ? (t >= 128 - sl) : (t < sl);
        const float hv = v ? (float)hh[(size_t)(t + 1) * 128 + j] : 0.f;
        const int s = dir ? (127 - t) : t;
        feats[((size_t)b * 128 + s) * 256 + dir * 128 + j] = hv;
    }
}

// ---------------------------------------------------------------------------
// CRF + finalize, fused: ONE block, 512 threads. Each 32-lane half owns one
// batch. Alpha broadcast via intra-32 shuffles; no __syncthreads in t-loop.
// Max/sum reductions as explicit register trees to shorten the serial chain.
// ---------------------------------------------------------------------------
__global__ __launch_bounds__(512)
void crf_kernel(const float* __restrict__ logits,  // [B*S][32]
                const int* __restrict__ label,     // [B*S]
                const int* __restrict__ seqlen,
                const float* __restrict__ T,       // [32][32]
                float* __restrict__ out)           // scalar
{
    const int tid = threadIdx.x;
    const int b   = tid >> 5;     // batch 0..15
    const int j   = tid & 31;

    float Tc[32];
#pragma unroll
    for (int i = 0; i < 32; ++i) Tc[i] = T[i * 32 + j];

    const float* lg = logits + (size_t)b * 128 * 32;
    const int* lab = label + b * 128;
    const int sl = seqlen[b];

    // gold score
    float g = 0.f;
#pragma unroll
    for (int r = 0; r < 4; ++r) {
        const int t = j + r * 32;
        if (t < sl) {
            g += lg[t * 32 + lab[t]];
            if (t >= 1) g += T[lab[t - 1] * 32 + lab[t]];
        }
    }
#pragma unroll
    for (int m = 16; m; m >>= 1) g += __shfl_xor(g, m, 32);

    float av = lg[j];
    for (int t = 1; t < 128; ++t) {
        float v[32];
#pragma unroll
        for (int i = 0; i < 32; ++i)
            v[i] = __shfl(av, i, 32) + Tc[i];
        // max tree (5 levels)
        float m16[16];
#pragma unroll
        for (int i = 0; i < 16; ++i) m16[i] = fmaxf(v[2 * i], v[2 * i + 1]);
        float m8[8];
#pragma unroll
        for (int i = 0; i < 8; ++i) m8[i] = fmaxf(m16[2 * i], m16[2 * i + 1]);
        float m4[4];
#pragma unroll
        for (int i = 0; i < 4; ++i) m4[i] = fmaxf(m8[2 * i], m8[2 * i + 1]);
        const float m2a = fmaxf(m4[0], m4[1]), m2b = fmaxf(m4[2], m4[3]);
        const float m = fmaxf(m2a, m2b);
        // exp + sum tree
        float e16[16];
#pragma unroll
        for (int i = 0; i < 16; ++i)
            e16[i] = __expf(v[2 * i] - m) + __expf(v[2 * i + 1] - m);
        float e8[8];
#pragma unroll
        for (int i = 0; i < 8; ++i) e8[i] = e16[2 * i] + e16[2 * i + 1];
        float e4[4];
#pragma unroll
        for (int i = 0; i < 4; ++i) e4[i] = e8[2 * i] + e8[2 * i + 1];
        const float s = (e4[0] + e4[1]) + (e4[2] + e4[3]);
        float nv = m + __logf(s) + lg[t * 32 + j];
        if (t >= sl) nv = av;
        av = nv;
    }
    // logZ over the half's 32 lanes
    float m2 = av;
#pragma unroll
    for (int m = 16; m; m >>= 1) m2 = fmaxf(m2, __shfl_xor(m2, m, 32));
    float s2 = __expf(av - m2);
#pragma unroll
    for (int m = 16; m; m >>= 1) s2 += __shfl_xor(s2, m, 32);

    __shared__ float partb[16];
    if (j == 0) partb[b] = (m2 + __logf(s2)) - g;
    __syncthreads();
    if (tid == 0) {
        float s = 0.f;
        for (int i = 0; i < 16; ++i) s += partb[i];
        out[0] = s * (1.f / 16.f);
    }
}

extern "C" void kernel_launch(void* const* d_in, const int* in_sizes, int n_in,
                              void* d_out, int out_size, void* d_ws, size_t ws_size,
                              hipStream_t stream)
{
    (void)in_sizes; (void)n_in; (void)out_size; (void)ws_size;
    const int*   char_ids    = (const int*)d_in[0];
    const int*   kb_word_ids = (const int*)d_in[1];
    const int*   word_begin  = (const int*)d_in[2];
    const int*   word_len    = (const int*)d_in[3];
    const int*   label       = (const int*)d_in[4];
    const int*   seqlen      = (const int*)d_in[5];
    const float* char_emb    = (const float*)d_in[6];
    const float* kb_emb      = (const float*)d_in[7];
    const float* dense_W     = (const float*)d_in[8];
    const float* dense_b     = (const float*)d_in[9];
    const float* crf_T       = (const float*)d_in[10];
    const float* f_Wcx = (const float*)d_in[11];
    const float* f_Wch = (const float*)d_in[12];
    const float* f_bc  = (const float*)d_in[13];
    const float* f_Wwx = (const float*)d_in[14];
    const float* f_Wwh = (const float*)d_in[15];
    const float* f_bw  = (const float*)d_in[16];
    const float* f_Wlx = (const float*)d_in[17];
    const float* f_Wlc = (const float*)d_in[18];
    const float* f_bl  = (const float*)d_in[19];
    const float* r_Wcx = (const float*)d_in[20];
    const float* r_Wch = (const float*)d_in[21];
    const float* r_bc  = (const float*)d_in[22];
    const float* r_Wwx = (const float*)d_in[23];
    const float* r_Wwh = (const float*)d_in[24];
    const float* r_bw  = (const float*)d_in[25];
    const float* r_Wlx = (const float*)d_in[26];
    const float* r_Wlc = (const float*)d_in[27];
    const float* r_bl  = (const float*)d_in[28];

    float* ws = (float*)d_ws;
    size_t o = 0;
    float* Xg     = ws + o; o += (size_t)2 * 2048 * 512;   // [dir][B*S][512]
    float* Xl     = ws + o; o += (size_t)2 * 2048 * 128;   // [dir][B*S][128]
    float* Wg     = ws + o; o += (size_t)2 * 1024 * 384;   // [dir][B*N][384]
    float* feats  = ws + o; o += (size_t)2048 * 256;       // [B*S][2H]
    float* logits = ws + o; o += (size_t)2048 * 32;

    gemm_char<<<dim3(256, 2), 256, 0, stream>>>(
        char_emb, char_ids, f_Wcx, r_Wcx, f_bc, r_bc,
        f_Wlx, r_Wlx, f_bl, r_bl, Xg, Xl);
    gemm_pair<128, 384, 8, 192><<<dim3(128, 2), 192, 0, stream>>>(
        kb_emb, kb_word_ids, f_Wwx, r_Wwx, f_bw, r_bw, Wg, 1024, 64, 0);

    lattice_kernel<<<32, 512, LAT_DYN_SMEM, stream>>>(
        Xg, Xl, Wg, f_Wch, r_Wch, f_Wwh, r_Wwh, f_Wlc, r_Wlc,
        word_begin, word_len, seqlen, feats);

    gemm_pair<256, 32, 16, 128><<<dim3(128, 1), 128, 0, stream>>>(
        feats, nullptr, dense_W, dense_W, dense_b, dense_b, logits, 2048, 128, 0);
    crf_kernel<<<1, 512, 0, stream>>>(logits, label, seqlen, crf_T, (float*)d_out);
}

// Round 9
// 529.685 us; speedup vs baseline: 1.0297x; 1.0297x over previous
//
#include <hip/hip_runtime.h>

// ---------------------------------------------------------------------------
// BiLstmCrf: bidirectional lattice-LSTM + CRF NLL -> one scalar.
//
//   1. gemm_char : Xg(f+r) AND Xl(f+r) from one staged char-emb gather
//   2. gemm_pair : Wg(f+r)
//   3. lattice_kernel : 32 WGs (one per (batch,dir)), 512 thr (8 waves).
//        ALL matvecs on the MFMA pipe (mfma_f32_16x16x32_f16, broadcast-A);
//        weights resident in VGPRs as B-fragments (~128 VGPR). h history
//        (f16) + c history (f32) in LDS. 1 lgkm-only barrier per eventless
//        step; straight-line E<=2 event path. [UNCHANGED — proven 184 us]
//   4. gemm_pair : logits = feats @ dense_W + dense_b
//   5. crf_kernel : 8 blocks x 64 thr (one batch per 32-lane half, 8 CUs),
//        shuffle-broadcast alpha, NO __syncthreads in the t-loop.
//   6. finalize_kernel
// ---------------------------------------------------------------------------

typedef _Float16 f16x8 __attribute__((ext_vector_type(8)));
typedef float    f32x4 __attribute__((ext_vector_type(4)));

__device__ __forceinline__ float sigm(float x) { return 1.f / (1.f + __expf(-x)); }
__device__ __forceinline__ float tanh_fast(float x) {
    return 1.f - 2.f / (__expf(2.f * x) + 1.f);
}
// lgkm-only barrier: LDS ops drained, vmem loads stay outstanding.
__device__ __forceinline__ void bar_lgkm() {
    asm volatile("s_waitcnt lgkmcnt(0)\n\ts_barrier" ::: "memory");
}

__device__ __forceinline__ f32x4 mfma16(f16x8 a, f16x8 b, f32x4 c) {
    return __builtin_amdgcn_mfma_f32_16x16x32_f16(a, b, c, 0, 0, 0);
}

// ---------------------------------------------------------------------------
// Combined char gemm: stage 8 rows of char_emb once, produce Xg (J=512) and
// Xl (J=128). blockIdx.y = direction (y=1 uses reversed row order + r_* W).
// ---------------------------------------------------------------------------
__global__ __launch_bounds__(256)
void gemm_char(const float* __restrict__ emb, const int* __restrict__ idx,
               const float* __restrict__ Wg0, const float* __restrict__ Wg1,
               const float* __restrict__ bg0, const float* __restrict__ bg1,
               const float* __restrict__ Wl0, const float* __restrict__ Wl1,
               const float* __restrict__ bl0, const float* __restrict__ bl1,
               float* __restrict__ outg, float* __restrict__ outl)
{
    constexpr int K = 128, RPB = 8, BLK = 256;
    const int y = blockIdx.y;
    const float* __restrict__ Wg = y ? Wg1 : Wg0;
    const float* __restrict__ bg = y ? bg1 : bg0;
    const float* __restrict__ Wl = y ? Wl1 : Wl0;
    const float* __restrict__ bl = y ? bl1 : bl0;
    float* __restrict__ og = outg + (size_t)y * 2048 * 512;
    float* __restrict__ ol = outl + (size_t)y * 2048 * 128;

    __shared__ __align__(16) float xs[RPB * K];
    __shared__ const float* srcs[RPB];
    const int tid = threadIdx.x;
    const int r0 = blockIdx.x * RPB;
    if (tid < RPB) {
        const int row = r0 + tid;
        const int bb = row >> 7, tt = row & 127;
        const int ts = y ? (127 - tt) : tt;
        srcs[tid] = emb + (size_t)idx[bb * 128 + ts] * K;
    }
    __syncthreads();
    constexpr int NQ = RPB * K / 4;
    for (int q = tid; q < NQ; q += BLK) {
        const int rr = q / (K / 4), qq = q - rr * (K / 4);
        ((float4*)xs)[q] = ((const float4*)srcs[rr])[qq];
    }
    __syncthreads();

    // ---- phase 1: J = 512 (Xg) -------------------------------------------
    {
        constexpr int NJ4 = 128, RT = BLK / NJ4, RPT = RPB / RT;  // 2, 4
        const int jq = tid % NJ4;
        const int rg = tid / NJ4;
        float4 acc[RPT];
#pragma unroll
        for (int r = 0; r < RPT; ++r) acc[r] = make_float4(0.f, 0.f, 0.f, 0.f);
        const float4* __restrict__ W4 = (const float4*)Wg;
#pragma unroll 4
        for (int k = 0; k < K; ++k) {
            const float4 wv = W4[(size_t)k * NJ4 + jq];
#pragma unroll
            for (int r = 0; r < RPT; ++r) {
                const float xv = xs[(rg * RPT + r) * K + k];
                acc[r].x = fmaf(xv, wv.x, acc[r].x);
                acc[r].y = fmaf(xv, wv.y, acc[r].y);
                acc[r].z = fmaf(xv, wv.z, acc[r].z);
                acc[r].w = fmaf(xv, wv.w, acc[r].w);
            }
        }
        const float4 bv = ((const float4*)bg)[jq];
#pragma unroll
        for (int r = 0; r < RPT; ++r) {
            const int row = r0 + rg * RPT + r;
            ((float4*)og)[(size_t)row * NJ4 + jq] =
                make_float4(acc[r].x + bv.x, acc[r].y + bv.y,
                            acc[r].z + bv.z, acc[r].w + bv.w);
        }
    }
    // ---- phase 2: J = 128 (Xl), xs unchanged -----------------------------
    {
        constexpr int NJ4 = 32;
        const int jq = tid % NJ4;
        const int rg = tid / NJ4;                                 // 0..7 = row
        float4 acc = make_float4(0.f, 0.f, 0.f, 0.f);
        const float4* __restrict__ W4 = (const float4*)Wl;
#pragma unroll 4
        for (int k = 0; k < K; ++k) {
            const float4 wv = W4[(size_t)k * NJ4 + jq];
            const float xv = xs[rg * K + k];
            acc.x = fmaf(xv, wv.x, acc.x);
            acc.y = fmaf(xv, wv.y, acc.y);
            acc.z = fmaf(xv, wv.z, acc.z);
            acc.w = fmaf(xv, wv.w, acc.w);
        }
        const float4 bv = ((const float4*)bl)[jq];
        const int row = r0 + rg;
        ((float4*)ol)[(size_t)row * NJ4 + jq] =
            make_float4(acc.x + bv.x, acc.y + bv.y, acc.z + bv.z, acc.w + bv.w);
    }
}

// ---------------------------------------------------------------------------
// Generic gemm (used for Wg and logits). Same as previous rounds.
// ---------------------------------------------------------------------------
template <int K, int J, int RPB, int BLK>
__global__ __launch_bounds__(BLK)
void gemm_pair(const float* __restrict__ emb, const int* __restrict__ idx,
               const float* __restrict__ W0, const float* __restrict__ W1,
               const float* __restrict__ b0, const float* __restrict__ b1,
               float* __restrict__ out, int rowsTotal, int Sdim, int revmode)
{
    constexpr int NJ4 = J / 4;
    constexpr int RT  = BLK / NJ4;
    constexpr int RPT = RPB / RT;
    static_assert(BLK % NJ4 == 0 && RPB % RT == 0, "layout");
    const int y = blockIdx.y;
    const float* __restrict__ W    = y ? W1 : W0;
    const float* __restrict__ bias = y ? b1 : b0;
    float* __restrict__ outp = out + (size_t)y * rowsTotal * J;
    const int rev = (revmode && y) ? 1 : 0;

    __shared__ __align__(16) float xs[RPB * K];
    __shared__ const float* srcs[RPB];
    const int tid = threadIdx.x;
    const int r0 = blockIdx.x * RPB;
    if (tid < RPB) {
        const int row = r0 + tid;
        const float* s = nullptr;
        if (row < rowsTotal) {
            if (idx) {
                const int bb = row / Sdim, tt = row - bb * Sdim;
                const int ts = rev ? (Sdim - 1 - tt) : tt;
                s = emb + (size_t)idx[bb * Sdim + ts] * K;
            } else {
                s = emb + (size_t)row * K;
            }
        }
        srcs[tid] = s;
    }
    __syncthreads();
    constexpr int NQ = RPB * K / 4;
    for (int q = tid; q < NQ; q += BLK) {
        const int rr = q / (K / 4), qq = q - rr * (K / 4);
        const float4* s = (const float4*)srcs[rr];
        ((float4*)xs)[q] = s ? s[qq] : make_float4(0.f, 0.f, 0.f, 0.f);
    }
    __syncthreads();

    const int jq = tid % NJ4;
    const int rg = tid / NJ4;
    float4 acc[RPT];
#pragma unroll
    for (int r = 0; r < RPT; ++r) acc[r] = make_float4(0.f, 0.f, 0.f, 0.f);
    const float4* __restrict__ W4 = (const float4*)W;
#pragma unroll 4
    for (int k = 0; k < K; ++k) {
        const float4 wv = W4[(size_t)k * NJ4 + jq];
#pragma unroll
        for (int r = 0; r < RPT; ++r) {
            const float xv = xs[(rg * RPT + r) * K + k];
            acc[r].x = fmaf(xv, wv.x, acc[r].x);
            acc[r].y = fmaf(xv, wv.y, acc[r].y);
            acc[r].z = fmaf(xv, wv.z, acc[r].z);
            acc[r].w = fmaf(xv, wv.w, acc[r].w);
        }
    }
    const float4 bv = ((const float4*)bias)[jq];
#pragma unroll
    for (int r = 0; r < RPT; ++r) {
        const int row = r0 + rg * RPT + r;
        if (row < rowsTotal)
            ((float4*)outp)[(size_t)row * NJ4 + jq] =
                make_float4(acc[r].x + bv.x, acc[r].y + bv.y,
                            acc[r].z + bv.z, acc[r].w + bv.w);
    }
}

// ---------------------------------------------------------------------------
// Lattice scan. One WG per (batch,dir). MFMA layout: wave wid owns columns
// jm = 16*wid + (lane&15). Dynamic LDS: hh (f16, 129*128) + ch (f32, 129*128).
// [UNCHANGED — proven 184 us]
// ---------------------------------------------------------------------------
#define HH_BYTES (129 * 128 * 2)
#define CH_BYTES (129 * 128 * 4)
#define LAT_DYN_SMEM (HH_BYTES + CH_BYTES)

__global__ __launch_bounds__(512, 2)
void lattice_kernel(const float* __restrict__ Xg,    // [2][B*S][512]
                    const float* __restrict__ Xl,    // [2][B*S][128]
                    const float* __restrict__ Wgp,   // [2][B*N][384]
                    const float* __restrict__ Wch_f, const float* __restrict__ Wch_r,
                    const float* __restrict__ Wwh_f, const float* __restrict__ Wwh_r,
                    const float* __restrict__ Wlc_f, const float* __restrict__ Wlc_r,
                    const int* __restrict__ word_begin, const int* __restrict__ word_len,
                    const int* __restrict__ seqlen,
                    float* __restrict__ feats)       // [B*S][256]
{
    extern __shared__ __align__(16) char dyn_smem[];
    _Float16* hh = (_Float16*)dyn_smem;                    // [129][128]
    float*    ch = (float*)(dyn_smem + HH_BYTES);          // [129][128]

    const int bdid = blockIdx.x;
    const int b = bdid >> 1, dir = bdid & 1;
    const int tid = threadIdx.x;
    const int wid = tid >> 6;     // wave 0..7
    const int ln  = tid & 63;     // lane
    const int lg  = ln >> 4;      // k-group 0..3 within MFMA operand
    const int jm  = wid * 16 + (ln & 15);   // owned column 0..127

    const float* Wch = dir ? Wch_r : Wch_f;
    const float* Wwh = dir ? Wwh_r : Wwh_f;
    const float* Wlc = dir ? Wlc_r : Wlc_f;

    // ---- weights -> VGPRs as MFMA B-fragments -----------------------------
    f16x8 Bc[4][4];   // [gate][kt]
#pragma unroll
    for (int g = 0; g < 4; ++g)
#pragma unroll
        for (int kt = 0; kt < 4; ++kt) {
            f16x8 v;
#pragma unroll
            for (int i = 0; i < 8; ++i)
                v[i] = (_Float16)Wch[(size_t)(kt * 32 + lg * 8 + i) * 512 + (g * 128 + jm)];
            Bc[g][kt] = v;
        }
    f16x8 Bw[3][4];   // [part][kt]
#pragma unroll
    for (int p = 0; p < 3; ++p)
#pragma unroll
        for (int kt = 0; kt < 4; ++kt) {
            f16x8 v;
#pragma unroll
            for (int i = 0; i < 8; ++i)
                v[i] = (_Float16)Wwh[(size_t)(kt * 32 + lg * 8 + i) * 384 + (p * 128 + jm)];
            Bw[p][kt] = v;
        }
    f16x8 Bl[4];      // [kt]
#pragma unroll
    for (int kt = 0; kt < 4; ++kt) {
        f16x8 v;
#pragma unroll
        for (int i = 0; i < 8; ++i)
            v[i] = (_Float16)Wlc[(size_t)(kt * 32 + lg * 8 + i) * 128 + jm];
        Bl[kt] = v;
    }

    // ---- static LDS --------------------------------------------------------
    __shared__ __align__(16) _Float16 cw2s[2][2][128];   // [chunk-parity][slot][col]
    __shared__ int ev_start[129];
    __shared__ int cnts[128];
    __shared__ int fills[128];
    __shared__ short ev_word[64];
    __shared__ short wbeg_s[64];

    const int sl = seqlen[b];

    // ---- event schedule ----------------------------------------------------
    if (tid < 128) { cnts[tid] = 0; fills[tid] = 0; }
    __syncthreads();
    int myvalid = 0, myed = 0;
    if (tid < 64) {
        const int bg = word_begin[b * 64 + tid];
        const int lnw = word_len[b * 64 + tid];
        int ef = bg + lnw; if (ef > 127) ef = 127;
        myvalid = (ef < sl);
        const int bd_ = dir ? (127 - ef) : bg;
        const int ed_ = dir ? (127 - bg) : ef;
        wbeg_s[tid] = (short)bd_;
        myed = ed_;
        if (myvalid) atomicAdd(&cnts[ed_], 1);
    }
    __syncthreads();
    if (tid == 0) {
        int run = 0; ev_start[0] = 0;
        for (int t = 0; t < 128; ++t) { run += cnts[t]; ev_start[t + 1] = run; }
    }
    __syncthreads();
    if (tid < 64 && myvalid) {
        const int pos = atomicAdd(&fills[myed], 1);
        ev_word[ev_start[myed] + pos] = (short)tid;
    }
    if (tid < 128) { hh[tid] = (_Float16)0.f; ch[tid] = 0.f; }   // slot 0
    __syncthreads();

    const float* Xg_b = Xg + ((size_t)dir * 2048 + (size_t)b * 128) * 512;
    const float* Xl_b = Xl + ((size_t)dir * 2048 + (size_t)b * 128) * 128;
    const float* Wg_b = Wgp + ((size_t)dir * 1024 + (size_t)b * 64) * 384;

    float h_reg = 0.f, c_reg = 0.f;

    // ---- pipeline registers: step-t event data prefetched at step t-1 ------
    int   curE, cur_ec0;
    int   cur_bgs[2] = {0, 0};
    float cur_wgp[2][3] = {};
    float xg_cur[4];
    {
        curE = ev_start[1];                // e0 = 0
        cur_ec0 = curE < 2 ? curE : 2;
#pragma unroll
        for (int s = 0; s < 2; ++s)
            if (s < cur_ec0) {
                const int wd = __builtin_amdgcn_readfirstlane((int)ev_word[s]);
                cur_bgs[s] = __builtin_amdgcn_readfirstlane((int)wbeg_s[wd]);
                const float* wgr = Wg_b + (size_t)wd * 384;
                cur_wgp[s][0] = wgr[jm];
                cur_wgp[s][1] = wgr[128 + jm];
                cur_wgp[s][2] = wgr[256 + jm];
            }
#pragma unroll
        for (int g = 0; g < 4; ++g) xg_cur[g] = Xg_b[g * 128 + jm];
    }

    for (int t = 0; t < 128; ++t) {
        // ---- A-fragments for char matvec: issue LDS reads first -----------
        f16x8 A[4];
#pragma unroll
        for (int kt = 0; kt < 4; ++kt)
            A[kt] = ((const f16x8*)hh)[t * 16 + kt * 4 + lg];

        // ---- Xl for current step (L2-resident; consumed after barrier) ----
        float xl = 0.f;
        if (curE > 0) xl = Xl_b[(size_t)t * 128 + jm];

        // ---- prefetch step t+1 (in flight across lgkm barriers) -----------
        int   nxtE = 0, nxt_ec0 = 0;
        int   nxt_bgs[2] = {0, 0};
        float nxt_wgp[2][3] = {};
        float xg_nxt[4] = {0.f, 0.f, 0.f, 0.f};
        if (t < 127) {
            const int e0n = ev_start[t + 1];
            nxtE = ev_start[t + 2] - e0n;
            nxt_ec0 = nxtE < 2 ? nxtE : 2;
#pragma unroll
            for (int s = 0; s < 2; ++s)
                if (s < nxt_ec0) {
                    const int wd = __builtin_amdgcn_readfirstlane((int)ev_word[e0n + s]);
                    nxt_bgs[s] = __builtin_amdgcn_readfirstlane((int)wbeg_s[wd]);
                    const float* wgr = Wg_b + (size_t)wd * 384;
                    nxt_wgp[s][0] = wgr[jm];
                    nxt_wgp[s][1] = wgr[128 + jm];
                    nxt_wgp[s][2] = wgr[256 + jm];
                }
#pragma unroll
            for (int g = 0; g < 4; ++g)
                xg_nxt[g] = Xg_b[(size_t)(t + 1) * 512 + g * 128 + jm];
        }

        // ---- char matvec: 16 MFMA, broadcast-A = h[t] ---------------------
        f32x4 d[4];
#pragma unroll
        for (int g = 0; g < 4; ++g) d[g] = (f32x4){0.f, 0.f, 0.f, 0.f};
#pragma unroll
        for (int kt = 0; kt < 4; ++kt)
#pragma unroll
            for (int g = 0; g < 4; ++g)
                d[g] = mfma16(A[kt], Bc[g][kt], d[g]);

        const float gi = sigm(d[0][0] + xg_cur[0]);
        const float gf = sigm(d[1][0] + xg_cur[1]);
        const float go = sigm(d[2][0] + xg_cur[2]);
        const float gg = tanh_fast(d[3][0] + xg_cur[3]);

        float accn = 0.f, accd = 0.f;
        if (curE > 0) {
            const int e0 = ev_start[t];
            // ---- first chunk (covers E<=2, the dominant case) -------------
            float cwreg[2] = {0.f, 0.f};
#pragma unroll
            for (int s = 0; s < 2; ++s)
                if (s < cur_ec0) {
                    f16x8 Ab[4];
#pragma unroll
                    for (int kt = 0; kt < 4; ++kt)
                        Ab[kt] = ((const f16x8*)hh)[cur_bgs[s] * 16 + kt * 4 + lg];
                    f32x4 ep[3];
#pragma unroll
                    for (int p = 0; p < 3; ++p) ep[p] = (f32x4){0.f, 0.f, 0.f, 0.f};
#pragma unroll
                    for (int kt = 0; kt < 4; ++kt)
#pragma unroll
                        for (int p = 0; p < 3; ++p)
                            ep[p] = mfma16(Ab[kt], Bw[p][kt], ep[p]);
                    const float wi = cur_wgp[s][0] + ep[0][0];
                    const float wf = cur_wgp[s][1] + ep[1][0];
                    const float wv = cur_wgp[s][2] + ep[2][0];
                    const float cb = ch[(size_t)cur_bgs[s] * 128 + jm];
                    const float cwv = sigm(wf) * cb + sigm(wi) * tanh_fast(wv);
                    cwreg[s] = cwv;
                    if (ln < 16) cw2s[0][s][jm] = (_Float16)cwv;
                }
            bar_lgkm();   // publish cw2s[0]
#pragma unroll
            for (int s = 0; s < 2; ++s)
                if (s < cur_ec0) {
                    f16x8 Ac[4];
#pragma unroll
                    for (int kt = 0; kt < 4; ++kt)
                        Ac[kt] = ((const f16x8*)(&cw2s[0][s][0]))[kt * 4 + lg];
                    f32x4 r = (f32x4){0.f, 0.f, 0.f, 0.f};
#pragma unroll
                    for (int kt = 0; kt < 4; ++kt)
                        r = mfma16(Ac[kt], Bl[kt], r);
                    const float lgv = sigm(xl + r[0]);
                    const float ew = __expf(lgv);
                    accn = fmaf(ew, cwreg[s], accn);
                    accd += ew;
                }
            // ---- rare tail: E > 2, simple sequential chunks ---------------
            for (int base2 = 2; base2 < curE; base2 += 2) {
                const int bb = (base2 >> 1) & 1;
                const int en = (curE - base2) < 2 ? (curE - base2) : 2;
                float cwr2[2] = {0.f, 0.f};
#pragma unroll
                for (int s = 0; s < 2; ++s)
                    if (s < en) {
                        const int wd = __builtin_amdgcn_readfirstlane((int)ev_word[e0 + base2 + s]);
                        const int bg2 = __builtin_amdgcn_readfirstlane((int)wbeg_s[wd]);
                        const float* wgr = Wg_b + (size_t)wd * 384;
                        const float wg0 = wgr[jm], wg1 = wgr[128 + jm], wg2 = wgr[256 + jm];
                        f16x8 Ab[4];
#pragma unroll
                        for (int kt = 0; kt < 4; ++kt)
                            Ab[kt] = ((const f16x8*)hh)[bg2 * 16 + kt * 4 + lg];
                        f32x4 ep[3];
#pragma unroll
                        for (int p = 0; p < 3; ++p) ep[p] = (f32x4){0.f, 0.f, 0.f, 0.f};
#pragma unroll
                        for (int kt = 0; kt < 4; ++kt)
#pragma unroll
                            for (int p = 0; p < 3; ++p)
                                ep[p] = mfma16(Ab[kt], Bw[p][kt], ep[p]);
                        const float wi = wg0 + ep[0][0];
                        const float wf = wg1 + ep[1][0];
                        const float wv = wg2 + ep[2][0];
                        const float cb = ch[(size_t)bg2 * 128 + jm];
                        const float cwv = sigm(wf) * cb + sigm(wi) * tanh_fast(wv);
                        cwr2[s] = cwv;
                        if (ln < 16) cw2s[bb][s][jm] = (_Float16)cwv;
                    }
                bar_lgkm();   // publish cw2s[bb]
#pragma unroll
                for (int s = 0; s < 2; ++s)
                    if (s < en) {
                        f16x8 Ac[4];
#pragma unroll
                        for (int kt = 0; kt < 4; ++kt)
                            Ac[kt] = ((const f16x8*)(&cw2s[bb][s][0]))[kt * 4 + lg];
                        f32x4 r = (f32x4){0.f, 0.f, 0.f, 0.f};
#pragma unroll
                        for (int kt = 0; kt < 4; ++kt)
                            r = mfma16(Ac[kt], Bl[kt], r);
                        const float lgv = sigm(xl + r[0]);
                        const float ew = __expf(lgv);
                        accn = fmaf(ew, cwr2[s], accn);
                        accd += ew;
                    }
            }
        }

        // ---- update (4 redundant lane-groups; group 0 writes) -------------
        float c_t;
        if (curE > 0) {
            const float ec = __expf(gi);
            c_t = (ec * gg + accn) / (ec + accd);
        } else {
            c_t = gf * c_reg + gi * gg;
        }
        const float h_t = go * tanh_fast(c_t);
        const bool v = dir ? (t >= 128 - sl) : (t < sl);
        const float hn = v ? h_t : h_reg;
        const float cn = v ? c_t : c_reg;
        h_reg = hn; c_reg = cn;
        if (ln < 16) {
            hh[(size_t)(t + 1) * 128 + jm] = (_Float16)hn;
            ch[(size_t)(t + 1) * 128 + jm] = cn;
        }

        // rotate pipeline
        curE = nxtE; cur_ec0 = nxt_ec0;
        cur_bgs[0] = nxt_bgs[0]; cur_bgs[1] = nxt_bgs[1];
#pragma unroll
        for (int s = 0; s < 2; ++s) {
            cur_wgp[s][0] = nxt_wgp[s][0];
            cur_wgp[s][1] = nxt_wgp[s][1];
            cur_wgp[s][2] = nxt_wgp[s][2];
        }
#pragma unroll
        for (int g = 0; g < 4; ++g) xg_cur[g] = xg_nxt[g];
        bar_lgkm();   // B: h/c (and cw2s buffers) visible for next step
    }

    // ---- epilogue: feats from LDS h history -------------------------------
    for (int i = tid; i < 128 * 128; i += 512) {
        const int t = i >> 7, j = i & 127;
        const bool v = dir ? (t >= 128 - sl) : (t < sl);
        const float hv = v ? (float)hh[(size_t)(t + 1) * 128 + j] : 0.f;
        const int s = dir ? (127 - t) : t;
        feats[((size_t)b * 128 + s) * 256 + dir * 128 + j] = hv;
    }
}

// ---------------------------------------------------------------------------
// CRF: 8 blocks x 64 thr (one batch per 32-lane half). Shuffle-broadcast
// alpha; NO __syncthreads in the t-loop. Max/sum as explicit register trees.
// ---------------------------------------------------------------------------
__global__ __launch_bounds__(64)
void crf_kernel(const float* __restrict__ logits,  // [B*S][32]
                const int* __restrict__ label,     // [B*S]
                const int* __restrict__ seqlen,
                const float* __restrict__ T,       // [32][32]
                float* __restrict__ out_part)      // [B]
{
    const int half = threadIdx.x >> 5;
    const int j    = threadIdx.x & 31;
    const int b    = blockIdx.x * 2 + half;

    float Tc[32];
#pragma unroll
    for (int i = 0; i < 32; ++i) Tc[i] = T[i * 32 + j];

    const float* lg = logits + (size_t)b * 128 * 32;
    const int* lab = label + b * 128;
    const int sl = seqlen[b];

    // gold score
    float g = 0.f;
#pragma unroll
    for (int r = 0; r < 4; ++r) {
        const int t = j + r * 32;
        if (t < sl) {
            g += lg[t * 32 + lab[t]];
            if (t >= 1) g += T[lab[t - 1] * 32 + lab[t]];
        }
    }
#pragma unroll
    for (int m = 16; m; m >>= 1) g += __shfl_xor(g, m, 32);

    float av = lg[j];
    for (int t = 1; t < 128; ++t) {
        float v[32];
#pragma unroll
        for (int i = 0; i < 32; ++i)
            v[i] = __shfl(av, i, 32) + Tc[i];
        // max tree (5 levels)
        float m16[16];
#pragma unroll
        for (int i = 0; i < 16; ++i) m16[i] = fmaxf(v[2 * i], v[2 * i + 1]);
        float m8[8];
#pragma unroll
        for (int i = 0; i < 8; ++i) m8[i] = fmaxf(m16[2 * i], m16[2 * i + 1]);
        float m4[4];
#pragma unroll
        for (int i = 0; i < 4; ++i) m4[i] = fmaxf(m8[2 * i], m8[2 * i + 1]);
        const float m2a = fmaxf(m4[0], m4[1]), m2b = fmaxf(m4[2], m4[3]);
        const float m = fmaxf(m2a, m2b);
        // exp + sum tree
        float e16[16];
#pragma unroll
        for (int i = 0; i < 16; ++i)
            e16[i] = __expf(v[2 * i] - m) + __expf(v[2 * i + 1] - m);
        float e8[8];
#pragma unroll
        for (int i = 0; i < 8; ++i) e8[i] = e16[2 * i] + e16[2 * i + 1];
        float e4[4];
#pragma unroll
        for (int i = 0; i < 4; ++i) e4[i] = e8[2 * i] + e8[2 * i + 1];
        const float s = (e4[0] + e4[1]) + (e4[2] + e4[3]);
        float nv = m + __logf(s) + lg[t * 32 + j];
        if (t >= sl) nv = av;
        av = nv;
    }
    // logZ over the half's 32 lanes
    float m2 = av;
#pragma unroll
    for (int m = 16; m; m >>= 1) m2 = fmaxf(m2, __shfl_xor(m2, m, 32));
    float s2 = __expf(av - m2);
#pragma unroll
    for (int m = 16; m; m >>= 1) s2 += __shfl_xor(s2, m, 32);
    if (j == 0) out_part[b] = (m2 + __logf(s2)) - g;
}

__global__ void finalize_kernel(const float* __restrict__ partb, float* __restrict__ out)
{
    if (threadIdx.x == 0 && blockIdx.x == 0) {
        float s = 0.f;
        for (int i = 0; i < 16; i++) s += partb[i];
        out[0] = s * (1.f / 16.f);
    }
}

extern "C" void kernel_launch(void* const* d_in, const int* in_sizes, int n_in,
                              void* d_out, int out_size, void* d_ws, size_t ws_size,
                              hipStream_t stream)
{
    (void)in_sizes; (void)n_in; (void)out_size; (void)ws_size;
    const int*   char_ids    = (const int*)d_in[0];
    const int*   kb_word_ids = (const int*)d_in[1];
    const int*   word_begin  = (const int*)d_in[2];
    const int*   word_len    = (const int*)d_in[3];
    const int*   label       = (const int*)d_in[4];
    const int*   seqlen      = (const int*)d_in[5];
    const float* char_emb    = (const float*)d_in[6];
    const float* kb_emb      = (const float*)d_in[7];
    const float* dense_W     = (const float*)d_in[8];
    const float* dense_b     = (const float*)d_in[9];
    const float* crf_T       = (const float*)d_in[10];
    const float* f_Wcx = (const float*)d_in[11];
    const float* f_Wch = (const float*)d_in[12];
    const float* f_bc  = (const float*)d_in[13];
    const float* f_Wwx = (const float*)d_in[14];
    const float* f_Wwh = (const float*)d_in[15];
    const float* f_bw  = (const float*)d_in[16];
    const float* f_Wlx = (const float*)d_in[17];
    const float* f_Wlc = (const float*)d_in[18];
    const float* f_bl  = (const float*)d_in[19];
    const float* r_Wcx = (const float*)d_in[20];
    const float* r_Wch = (const float*)d_in[21];
    const float* r_bc  = (const float*)d_in[22];
    const float* r_Wwx = (const float*)d_in[23];
    const float* r_Wwh = (const float*)d_in[24];
    const float* r_bw  = (const float*)d_in[25];
    const float* r_Wlx = (const float*)d_in[26];
    const float* r_Wlc = (const float*)d_in[27];
    const float* r_bl  = (const float*)d_in[28];

    float* ws = (float*)d_ws;
    size_t o = 0;
    float* Xg     = ws + o; o += (size_t)2 * 2048 * 512;   // [dir][B*S][512]
    float* Xl     = ws + o; o += (size_t)2 * 2048 * 128;   // [dir][B*S][128]
    float* Wg     = ws + o; o += (size_t)2 * 1024 * 384;   // [dir][B*N][384]
    float* feats  = ws + o; o += (size_t)2048 * 256;       // [B*S][2H]
    float* logits = ws + o; o += (size_t)2048 * 32;
    float* partb  = ws + o; o += 16;

    gemm_char<<<dim3(256, 2), 256, 0, stream>>>(
        char_emb, char_ids, f_Wcx, r_Wcx, f_bc, r_bc,
        f_Wlx, r_Wlx, f_bl, r_bl, Xg, Xl);
    gemm_pair<128, 384, 8, 192><<<dim3(128, 2), 192, 0, stream>>>(
        kb_emb, kb_word_ids, f_Wwx, r_Wwx, f_bw, r_bw, Wg, 1024, 64, 0);

    lattice_kernel<<<32, 512, LAT_DYN_SMEM, stream>>>(
        Xg, Xl, Wg, f_Wch, r_Wch, f_Wwh, r_Wwh, f_Wlc, r_Wlc,
        word_begin, word_len, seqlen, feats);

    gemm_pair<256, 32, 16, 128><<<dim3(128, 1), 128, 0, stream>>>(
        feats, nullptr, dense_W, dense_W, dense_b, dense_b, logits, 2048, 128, 0);
    crf_kernel<<<8, 64, 0, stream>>>(logits, label, seqlen, crf_T, partb);
    finalize_kernel<<<1, 64, 0, stream>>>(partb, (float*)d_out);
}

// Round 10
// 496.375 us; speedup vs baseline: 1.0988x; 1.0671x over previous
//
#include <hip/hip_runtime.h>

// ---------------------------------------------------------------------------
// BiLstmCrf: bidirectional lattice-LSTM + CRF NLL -> one scalar.
//
//   1. gemm_char : Xg(f+r) AND Xl(f+r) from one staged char-emb gather
//   2. gemm_pair : Wg(f+r)
//   3. lattice_kernel : 32 WGs (one per (batch,dir)), 512 thr (8 waves).
//        ALL matvecs on the MFMA pipe (mfma_f32_16x16x32_f16, broadcast-A);
//        weights resident in VGPRs as B-fragments (~128 VGPR). h history
//        (f16) + c history (f32) in LDS. 1 lgkm-only barrier per eventless
//        step; straight-line E<=2 event path. [UNCHANGED — proven 184 us]
//   4. gemm_pair : logits = feats @ dense_W + dense_b
//   5. crf_kernel : 8 blocks x 64 thr (one batch per 32-lane half, 8 CUs),
//        LDS-broadcast alpha (float4), 2 small-block barriers per step.
//        [R7 form — best measured total 514 us]
//   6. finalize_kernel
// ---------------------------------------------------------------------------

typedef _Float16 f16x8 __attribute__((ext_vector_type(8)));
typedef float    f32x4 __attribute__((ext_vector_type(4)));

__device__ __forceinline__ float sigm(float x) { return 1.f / (1.f + __expf(-x)); }
__device__ __forceinline__ float tanh_fast(float x) {
    return 1.f - 2.f / (__expf(2.f * x) + 1.f);
}
// lgkm-only barrier: LDS ops drained, vmem loads stay outstanding.
__device__ __forceinline__ void bar_lgkm() {
    asm volatile("s_waitcnt lgkmcnt(0)\n\ts_barrier" ::: "memory");
}

__device__ __forceinline__ f32x4 mfma16(f16x8 a, f16x8 b, f32x4 c) {
    return __builtin_amdgcn_mfma_f32_16x16x32_f16(a, b, c, 0, 0, 0);
}

// ---------------------------------------------------------------------------
// Combined char gemm: stage 8 rows of char_emb once, produce Xg (J=512) and
// Xl (J=128). blockIdx.y = direction (y=1 uses reversed row order + r_* W).
// ---------------------------------------------------------------------------
__global__ __launch_bounds__(256)
void gemm_char(const float* __restrict__ emb, const int* __restrict__ idx,
               const float* __restrict__ Wg0, const float* __restrict__ Wg1,
               const float* __restrict__ bg0, const float* __restrict__ bg1,
               const float* __restrict__ Wl0, const float* __restrict__ Wl1,
               const float* __restrict__ bl0, const float* __restrict__ bl1,
               float* __restrict__ outg, float* __restrict__ outl)
{
    constexpr int K = 128, RPB = 8, BLK = 256;
    const int y = blockIdx.y;
    const float* __restrict__ Wg = y ? Wg1 : Wg0;
    const float* __restrict__ bg = y ? bg1 : bg0;
    const float* __restrict__ Wl = y ? Wl1 : Wl0;
    const float* __restrict__ bl = y ? bl1 : bl0;
    float* __restrict__ og = outg + (size_t)y * 2048 * 512;
    float* __restrict__ ol = outl + (size_t)y * 2048 * 128;

    __shared__ __align__(16) float xs[RPB * K];
    __shared__ const float* srcs[RPB];
    const int tid = threadIdx.x;
    const int r0 = blockIdx.x * RPB;
    if (tid < RPB) {
        const int row = r0 + tid;
        const int bb = row >> 7, tt = row & 127;
        const int ts = y ? (127 - tt) : tt;
        srcs[tid] = emb + (size_t)idx[bb * 128 + ts] * K;
    }
    __syncthreads();
    constexpr int NQ = RPB * K / 4;
    for (int q = tid; q < NQ; q += BLK) {
        const int rr = q / (K / 4), qq = q - rr * (K / 4);
        ((float4*)xs)[q] = ((const float4*)srcs[rr])[qq];
    }
    __syncthreads();

    // ---- phase 1: J = 512 (Xg) -------------------------------------------
    {
        constexpr int NJ4 = 128, RT = BLK / NJ4, RPT = RPB / RT;  // 2, 4
        const int jq = tid % NJ4;
        const int rg = tid / NJ4;
        float4 acc[RPT];
#pragma unroll
        for (int r = 0; r < RPT; ++r) acc[r] = make_float4(0.f, 0.f, 0.f, 0.f);
        const float4* __restrict__ W4 = (const float4*)Wg;
#pragma unroll 4
        for (int k = 0; k < K; ++k) {
            const float4 wv = W4[(size_t)k * NJ4 + jq];
#pragma unroll
            for (int r = 0; r < RPT; ++r) {
                const float xv = xs[(rg * RPT + r) * K + k];
                acc[r].x = fmaf(xv, wv.x, acc[r].x);
                acc[r].y = fmaf(xv, wv.y, acc[r].y);
                acc[r].z = fmaf(xv, wv.z, acc[r].z);
                acc[r].w = fmaf(xv, wv.w, acc[r].w);
            }
        }
        const float4 bv = ((const float4*)bg)[jq];
#pragma unroll
        for (int r = 0; r < RPT; ++r) {
            const int row = r0 + rg * RPT + r;
            ((float4*)og)[(size_t)row * NJ4 + jq] =
                make_float4(acc[r].x + bv.x, acc[r].y + bv.y,
                            acc[r].z + bv.z, acc[r].w + bv.w);
        }
    }
    // ---- phase 2: J = 128 (Xl), xs unchanged -----------------------------
    {
        constexpr int NJ4 = 32;
        const int jq = tid % NJ4;
        const int rg = tid / NJ4;                                 // 0..7 = row
        float4 acc = make_float4(0.f, 0.f, 0.f, 0.f);
        const float4* __restrict__ W4 = (const float4*)Wl;
#pragma unroll 4
        for (int k = 0; k < K; ++k) {
            const float4 wv = W4[(size_t)k * NJ4 + jq];
            const float xv = xs[rg * K + k];
            acc.x = fmaf(xv, wv.x, acc.x);
            acc.y = fmaf(xv, wv.y, acc.y);
            acc.z = fmaf(xv, wv.z, acc.z);
            acc.w = fmaf(xv, wv.w, acc.w);
        }
        const float4 bv = ((const float4*)bl)[jq];
        const int row = r0 + rg;
        ((float4*)ol)[(size_t)row * NJ4 + jq] =
            make_float4(acc.x + bv.x, acc.y + bv.y, acc.z + bv.z, acc.w + bv.w);
    }
}

// ---------------------------------------------------------------------------
// Generic gemm (used for Wg and logits). Same as previous rounds.
// ---------------------------------------------------------------------------
template <int K, int J, int RPB, int BLK>
__global__ __launch_bounds__(BLK)
void gemm_pair(const float* __restrict__ emb, const int* __restrict__ idx,
               const float* __restrict__ W0, const float* __restrict__ W1,
               const float* __restrict__ b0, const float* __restrict__ b1,
               float* __restrict__ out, int rowsTotal, int Sdim, int revmode)
{
    constexpr int NJ4 = J / 4;
    constexpr int RT  = BLK / NJ4;
    constexpr int RPT = RPB / RT;
    static_assert(BLK % NJ4 == 0 && RPB % RT == 0, "layout");
    const int y = blockIdx.y;
    const float* __restrict__ W    = y ? W1 : W0;
    const float* __restrict__ bias = y ? b1 : b0;
    float* __restrict__ outp = out + (size_t)y * rowsTotal * J;
    const int rev = (revmode && y) ? 1 : 0;

    __shared__ __align__(16) float xs[RPB * K];
    __shared__ const float* srcs[RPB];
    const int tid = threadIdx.x;
    const int r0 = blockIdx.x * RPB;
    if (tid < RPB) {
        const int row = r0 + tid;
        const float* s = nullptr;
        if (row < rowsTotal) {
            if (idx) {
                const int bb = row / Sdim, tt = row - bb * Sdim;
                const int ts = rev ? (Sdim - 1 - tt) : tt;
                s = emb + (size_t)idx[bb * Sdim + ts] * K;
            } else {
                s = emb + (size_t)row * K;
            }
        }
        srcs[tid] = s;
    }
    __syncthreads();
    constexpr int NQ = RPB * K / 4;
    for (int q = tid; q < NQ; q += BLK) {
        const int rr = q / (K / 4), qq = q - rr * (K / 4);
        const float4* s = (const float4*)srcs[rr];
        ((float4*)xs)[q] = s ? s[qq] : make_float4(0.f, 0.f, 0.f, 0.f);
    }
    __syncthreads();

    const int jq = tid % NJ4;
    const int rg = tid / NJ4;
    float4 acc[RPT];
#pragma unroll
    for (int r = 0; r < RPT; ++r) acc[r] = make_float4(0.f, 0.f, 0.f, 0.f);
    const float4* __restrict__ W4 = (const float4*)W;
#pragma unroll 4
    for (int k = 0; k < K; ++k) {
        const float4 wv = W4[(size_t)k * NJ4 + jq];
#pragma unroll
        for (int r = 0; r < RPT; ++r) {
            const float xv = xs[(rg * RPT + r) * K + k];
            acc[r].x = fmaf(xv, wv.x, acc[r].x);
            acc[r].y = fmaf(xv, wv.y, acc[r].y);
            acc[r].z = fmaf(xv, wv.z, acc[r].z);
            acc[r].w = fmaf(xv, wv.w, acc[r].w);
        }
    }
    const float4 bv = ((const float4*)bias)[jq];
#pragma unroll
    for (int r = 0; r < RPT; ++r) {
        const int row = r0 + rg * RPT + r;
        if (row < rowsTotal)
            ((float4*)outp)[(size_t)row * NJ4 + jq] =
                make_float4(acc[r].x + bv.x, acc[r].y + bv.y,
                            acc[r].z + bv.z, acc[r].w + bv.w);
    }
}

// ---------------------------------------------------------------------------
// Lattice scan. One WG per (batch,dir). MFMA layout: wave wid owns columns
// jm = 16*wid + (lane&15). Dynamic LDS: hh (f16, 129*128) + ch (f32, 129*128).
// [UNCHANGED — proven 184 us]
// ---------------------------------------------------------------------------
#define HH_BYTES (129 * 128 * 2)
#define CH_BYTES (129 * 128 * 4)
#define LAT_DYN_SMEM (HH_BYTES + CH_BYTES)

__global__ __launch_bounds__(512, 2)
void lattice_kernel(const float* __restrict__ Xg,    // [2][B*S][512]
                    const float* __restrict__ Xl,    // [2][B*S][128]
                    const float* __restrict__ Wgp,   // [2][B*N][384]
                    const float* __restrict__ Wch_f, const float* __restrict__ Wch_r,
                    const float* __restrict__ Wwh_f, const float* __restrict__ Wwh_r,
                    const float* __restrict__ Wlc_f, const float* __restrict__ Wlc_r,
                    const int* __restrict__ word_begin, const int* __restrict__ word_len,
                    const int* __restrict__ seqlen,
                    float* __restrict__ feats)       // [B*S][256]
{
    extern __shared__ __align__(16) char dyn_smem[];
    _Float16* hh = (_Float16*)dyn_smem;                    // [129][128]
    float*    ch = (float*)(dyn_smem + HH_BYTES);          // [129][128]

    const int bdid = blockIdx.x;
    const int b = bdid >> 1, dir = bdid & 1;
    const int tid = threadIdx.x;
    const int wid = tid >> 6;     // wave 0..7
    const int ln  = tid & 63;     // lane
    const int lg  = ln >> 4;      // k-group 0..3 within MFMA operand
    const int jm  = wid * 16 + (ln & 15);   // owned column 0..127

    const float* Wch = dir ? Wch_r : Wch_f;
    const float* Wwh = dir ? Wwh_r : Wwh_f;
    const float* Wlc = dir ? Wlc_r : Wlc_f;

    // ---- weights -> VGPRs as MFMA B-fragments -----------------------------
    f16x8 Bc[4][4];   // [gate][kt]
#pragma unroll
    for (int g = 0; g < 4; ++g)
#pragma unroll
        for (int kt = 0; kt < 4; ++kt) {
            f16x8 v;
#pragma unroll
            for (int i = 0; i < 8; ++i)
                v[i] = (_Float16)Wch[(size_t)(kt * 32 + lg * 8 + i) * 512 + (g * 128 + jm)];
            Bc[g][kt] = v;
        }
    f16x8 Bw[3][4];   // [part][kt]
#pragma unroll
    for (int p = 0; p < 3; ++p)
#pragma unroll
        for (int kt = 0; kt < 4; ++kt) {
            f16x8 v;
#pragma unroll
            for (int i = 0; i < 8; ++i)
                v[i] = (_Float16)Wwh[(size_t)(kt * 32 + lg * 8 + i) * 384 + (p * 128 + jm)];
            Bw[p][kt] = v;
        }
    f16x8 Bl[4];      // [kt]
#pragma unroll
    for (int kt = 0; kt < 4; ++kt) {
        f16x8 v;
#pragma unroll
        for (int i = 0; i < 8; ++i)
            v[i] = (_Float16)Wlc[(size_t)(kt * 32 + lg * 8 + i) * 128 + jm];
        Bl[kt] = v;
    }

    // ---- static LDS --------------------------------------------------------
    __shared__ __align__(16) _Float16 cw2s[2][2][128];   // [chunk-parity][slot][col]
    __shared__ int ev_start[129];
    __shared__ int cnts[128];
    __shared__ int fills[128];
    __shared__ short ev_word[64];
    __shared__ short wbeg_s[64];

    const int sl = seqlen[b];

    // ---- event schedule ----------------------------------------------------
    if (tid < 128) { cnts[tid] = 0; fills[tid] = 0; }
    __syncthreads();
    int myvalid = 0, myed = 0;
    if (tid < 64) {
        const int bg = word_begin[b * 64 + tid];
        const int lnw = word_len[b * 64 + tid];
        int ef = bg + lnw; if (ef > 127) ef = 127;
        myvalid = (ef < sl);
        const int bd_ = dir ? (127 - ef) : bg;
        const int ed_ = dir ? (127 - bg) : ef;
        wbeg_s[tid] = (short)bd_;
        myed = ed_;
        if (myvalid) atomicAdd(&cnts[ed_], 1);
    }
    __syncthreads();
    if (tid == 0) {
        int run = 0; ev_start[0] = 0;
        for (int t = 0; t < 128; ++t) { run += cnts[t]; ev_start[t + 1] = run; }
    }
    __syncthreads();
    if (tid < 64 && myvalid) {
        const int pos = atomicAdd(&fills[myed], 1);
        ev_word[ev_start[myed] + pos] = (short)tid;
    }
    if (tid < 128) { hh[tid] = (_Float16)0.f; ch[tid] = 0.f; }   // slot 0
    __syncthreads();

    const float* Xg_b = Xg + ((size_t)dir * 2048 + (size_t)b * 128) * 512;
    const float* Xl_b = Xl + ((size_t)dir * 2048 + (size_t)b * 128) * 128;
    const float* Wg_b = Wgp + ((size_t)dir * 1024 + (size_t)b * 64) * 384;

    float h_reg = 0.f, c_reg = 0.f;

    // ---- pipeline registers: step-t event data prefetched at step t-1 ------
    int   curE, cur_ec0;
    int   cur_bgs[2] = {0, 0};
    float cur_wgp[2][3] = {};
    float xg_cur[4];
    {
        curE = ev_start[1];                // e0 = 0
        cur_ec0 = curE < 2 ? curE : 2;
#pragma unroll
        for (int s = 0; s < 2; ++s)
            if (s < cur_ec0) {
                const int wd = __builtin_amdgcn_readfirstlane((int)ev_word[s]);
                cur_bgs[s] = __builtin_amdgcn_readfirstlane((int)wbeg_s[wd]);
                const float* wgr = Wg_b + (size_t)wd * 384;
                cur_wgp[s][0] = wgr[jm];
                cur_wgp[s][1] = wgr[128 + jm];
                cur_wgp[s][2] = wgr[256 + jm];
            }
#pragma unroll
        for (int g = 0; g < 4; ++g) xg_cur[g] = Xg_b[g * 128 + jm];
    }

    for (int t = 0; t < 128; ++t) {
        // ---- A-fragments for char matvec: issue LDS reads first -----------
        f16x8 A[4];
#pragma unroll
        for (int kt = 0; kt < 4; ++kt)
            A[kt] = ((const f16x8*)hh)[t * 16 + kt * 4 + lg];

        // ---- Xl for current step (L2-resident; consumed after barrier) ----
        float xl = 0.f;
        if (curE > 0) xl = Xl_b[(size_t)t * 128 + jm];

        // ---- prefetch step t+1 (in flight across lgkm barriers) -----------
        int   nxtE = 0, nxt_ec0 = 0;
        int   nxt_bgs[2] = {0, 0};
        float nxt_wgp[2][3] = {};
        float xg_nxt[4] = {0.f, 0.f, 0.f, 0.f};
        if (t < 127) {
            const int e0n = ev_start[t + 1];
            nxtE = ev_start[t + 2] - e0n;
            nxt_ec0 = nxtE < 2 ? nxtE : 2;
#pragma unroll
            for (int s = 0; s < 2; ++s)
                if (s < nxt_ec0) {
                    const int wd = __builtin_amdgcn_readfirstlane((int)ev_word[e0n + s]);
                    nxt_bgs[s] = __builtin_amdgcn_readfirstlane((int)wbeg_s[wd]);
                    const float* wgr = Wg_b + (size_t)wd * 384;
                    nxt_wgp[s][0] = wgr[jm];
                    nxt_wgp[s][1] = wgr[128 + jm];
                    nxt_wgp[s][2] = wgr[256 + jm];
                }
#pragma unroll
            for (int g = 0; g < 4; ++g)
                xg_nxt[g] = Xg_b[(size_t)(t + 1) * 512 + g * 128 + jm];
        }

        // ---- char matvec: 16 MFMA, broadcast-A = h[t] ---------------------
        f32x4 d[4];
#pragma unroll
        for (int g = 0; g < 4; ++g) d[g] = (f32x4){0.f, 0.f, 0.f, 0.f};
#pragma unroll
        for (int kt = 0; kt < 4; ++kt)
#pragma unroll
            for (int g = 0; g < 4; ++g)
                d[g] = mfma16(A[kt], Bc[g][kt], d[g]);

        const float gi = sigm(d[0][0] + xg_cur[0]);
        const float gf = sigm(d[1][0] + xg_cur[1]);
        const float go = sigm(d[2][0] + xg_cur[2]);
        const float gg = tanh_fast(d[3][0] + xg_cur[3]);

        float accn = 0.f, accd = 0.f;
        if (curE > 0) {
            const int e0 = ev_start[t];
            // ---- first chunk (covers E<=2, the dominant case) -------------
            float cwreg[2] = {0.f, 0.f};
#pragma unroll
            for (int s = 0; s < 2; ++s)
                if (s < cur_ec0) {
                    f16x8 Ab[4];
#pragma unroll
                    for (int kt = 0; kt < 4; ++kt)
                        Ab[kt] = ((const f16x8*)hh)[cur_bgs[s] * 16 + kt * 4 + lg];
                    f32x4 ep[3];
#pragma unroll
                    for (int p = 0; p < 3; ++p) ep[p] = (f32x4){0.f, 0.f, 0.f, 0.f};
#pragma unroll
                    for (int kt = 0; kt < 4; ++kt)
#pragma unroll
                        for (int p = 0; p < 3; ++p)
                            ep[p] = mfma16(Ab[kt], Bw[p][kt], ep[p]);
                    const float wi = cur_wgp[s][0] + ep[0][0];
                    const float wf = cur_wgp[s][1] + ep[1][0];
                    const float wv = cur_wgp[s][2] + ep[2][0];
                    const float cb = ch[(size_t)cur_bgs[s] * 128 + jm];
                    const float cwv = sigm(wf) * cb + sigm(wi) * tanh_fast(wv);
                    cwreg[s] = cwv;
                    if (ln < 16) cw2s[0][s][jm] = (_Float16)cwv;
                }
            bar_lgkm();   // publish cw2s[0]
#pragma unroll
            for (int s = 0; s < 2; ++s)
                if (s < cur_ec0) {
                    f16x8 Ac[4];
#pragma unroll
                    for (int kt = 0; kt < 4; ++kt)
                        Ac[kt] = ((const f16x8*)(&cw2s[0][s][0]))[kt * 4 + lg];
                    f32x4 r = (f32x4){0.f, 0.f, 0.f, 0.f};
#pragma unroll
                    for (int kt = 0; kt < 4; ++kt)
                        r = mfma16(Ac[kt], Bl[kt], r);
                    const float lgv = sigm(xl + r[0]);
                    const float ew = __expf(lgv);
                    accn = fmaf(ew, cwreg[s], accn);
                    accd += ew;
                }
            // ---- rare tail: E > 2, simple sequential chunks ---------------
            for (int base2 = 2; base2 < curE; base2 += 2) {
                const int bb = (base2 >> 1) & 1;
                const int en = (curE - base2) < 2 ? (curE - base2) : 2;
                float cwr2[2] = {0.f, 0.f};
#pragma unroll
                for (int s = 0; s < 2; ++s)
                    if (s < en) {
                        const int wd = __builtin_amdgcn_readfirstlane((int)ev_word[e0 + base2 + s]);
                        const int bg2 = __builtin_amdgcn_readfirstlane((int)wbeg_s[wd]);
                        const float* wgr = Wg_b + (size_t)wd * 384;
                        const float wg0 = wgr[jm], wg1 = wgr[128 + jm], wg2 = wgr[256 + jm];
                        f16x8 Ab[4];
#pragma unroll
                        for (int kt = 0; kt < 4; ++kt)
                            Ab[kt] = ((const f16x8*)hh)[bg2 * 16 + kt * 4 + lg];
                        f32x4 ep[3];
#pragma unroll
                        for (int p = 0; p < 3; ++p) ep[p] = (f32x4){0.f, 0.f, 0.f, 0.f};
#pragma unroll
                        for (int kt = 0; kt < 4; ++kt)
#pragma unroll
                            for (int p = 0; p < 3; ++p)
                                ep[p] = mfma16(Ab[kt], Bw[p][kt], ep[p]);
                        const float wi = wg0 + ep[0][0];
                        const float wf = wg1 + ep[1][0];
                        const float wv = wg2 + ep[2][0];
                        const float cb = ch[(size_t)bg2 * 128 + jm];
                        const float cwv = sigm(wf) * cb + sigm(wi) * tanh_fast(wv);
                        cwr2[s] = cwv;
                        if (ln < 16) cw2s[bb][s][jm] = (_Float16)cwv;
                    }
                bar_lgkm();   // publish cw2s[bb]
#pragma unroll
                for (int s = 0; s < 2; ++s)
                    if (s < en) {
                        f16x8 Ac[4];
#pragma unroll
                        for (int kt = 0; kt < 4; ++kt)
                            Ac[kt] = ((const f16x8*)(&cw2s[bb][s][0]))[kt * 4 + lg];
                        f32x4 r = (f32x4){0.f, 0.f, 0.f, 0.f};
#pragma unroll
                        for (int kt = 0; kt < 4; ++kt)
                            r = mfma16(Ac[kt], Bl[kt], r);
                        const float lgv = sigm(xl + r[0]);
                        const float ew = __expf(lgv);
                        accn = fmaf(ew, cwr2[s], accn);
                        accd += ew;
                    }
            }
        }

        // ---- update (4 redundant lane-groups; group 0 writes) -------------
        float c_t;
        if (curE > 0) {
            const float ec = __expf(gi);
            c_t = (ec * gg + accn) / (ec + accd);
        } else {
            c_t = gf * c_reg + gi * gg;
        }
        const float h_t = go * tanh_fast(c_t);
        const bool v = dir ? (t >= 128 - sl) : (t < sl);
        const float hn = v ? h_t : h_reg;
        const float cn = v ? c_t : c_reg;
        h_reg = hn; c_reg = cn;
        if (ln < 16) {
            hh[(size_t)(t + 1) * 128 + jm] = (_Float16)hn;
            ch[(size_t)(t + 1) * 128 + jm] = cn;
        }

        // rotate pipeline
        curE = nxtE; cur_ec0 = nxt_ec0;
        cur_bgs[0] = nxt_bgs[0]; cur_bgs[1] = nxt_bgs[1];
#pragma unroll
        for (int s = 0; s < 2; ++s) {
            cur_wgp[s][0] = nxt_wgp[s][0];
            cur_wgp[s][1] = nxt_wgp[s][1];
            cur_wgp[s][2] = nxt_wgp[s][2];
        }
#pragma unroll
        for (int g = 0; g < 4; ++g) xg_cur[g] = xg_nxt[g];
        bar_lgkm();   // B: h/c (and cw2s buffers) visible for next step
    }

    // ---- epilogue: feats from LDS h history -------------------------------
    for (int i = tid; i < 128 * 128; i += 512) {
        const int t = i >> 7, j = i & 127;
        const bool v = dir ? (t >= 128 - sl) : (t < sl);
        const float hv = v ? (float)hh[(size_t)(t + 1) * 128 + j] : 0.f;
        const int s = dir ? (127 - t) : t;
        feats[((size_t)b * 128 + s) * 256 + dir * 128 + j] = hv;
    }
}

// ---------------------------------------------------------------------------
// CRF: 2 batches per 64-thread block (one per 32-lane half). T columns in
// registers; alpha broadcast via LDS float4. [R7 form — best measured]
// ---------------------------------------------------------------------------
__global__ void crf_kernel(const float* __restrict__ logits,  // [B*S][32]
                           const int* __restrict__ label,     // [B*S]
                           const int* __restrict__ seqlen,
                           const float* __restrict__ T,       // [32][32]
                           float* __restrict__ out_part)      // [B]
{
    const int half = threadIdx.x >> 5;
    const int j    = threadIdx.x & 31;
    const int b    = blockIdx.x * 2 + half;

    float Tc[32];
#pragma unroll
    for (int i = 0; i < 32; ++i) Tc[i] = T[i * 32 + j];

    const float* lg = logits + (size_t)b * 128 * 32;
    const int* lab = label + b * 128;
    const int sl = seqlen[b];

    // gold score
    float g = 0.f;
#pragma unroll
    for (int r = 0; r < 4; ++r) {
        const int t = j + r * 32;
        if (t < sl) {
            g += lg[t * 32 + lab[t]];
            if (t >= 1) g += T[lab[t - 1] * 32 + lab[t]];
        }
    }
#pragma unroll
    for (int m = 16; m; m >>= 1) g += __shfl_xor(g, m, 32);

    __shared__ __align__(16) float alpha_s[2][32];
    float av = lg[j];
    alpha_s[half][j] = av;
    __syncthreads();
    for (int t = 1; t < 128; ++t) {
        float a[32];
        const float4* ap = (const float4*)alpha_s[half];
#pragma unroll
        for (int q = 0; q < 8; ++q) {
            const float4 v = ap[q];
            a[4 * q] = v.x; a[4 * q + 1] = v.y; a[4 * q + 2] = v.z; a[4 * q + 3] = v.w;
        }
        float m = -1e30f;
#pragma unroll
        for (int i = 0; i < 32; ++i) m = fmaxf(m, a[i] + Tc[i]);
        float s = 0.f;
#pragma unroll
        for (int i = 0; i < 32; ++i) s += __expf(a[i] + Tc[i] - m);
        float nv = m + __logf(s) + lg[t * 32 + j];
        if (t >= sl) nv = av;
        av = nv;
        __syncthreads();
        alpha_s[half][j] = av;
        __syncthreads();
    }
    // logZ over the half's 32 lanes
    float m2 = av;
#pragma unroll
    for (int m = 16; m; m >>= 1) m2 = fmaxf(m2, __shfl_xor(m2, m, 32));
    float s2 = __expf(av - m2);
#pragma unroll
    for (int m = 16; m; m >>= 1) s2 += __shfl_xor(s2, m, 32);
    if (j == 0) out_part[b] = (m2 + __logf(s2)) - g;
}

__global__ void finalize_kernel(const float* __restrict__ partb, float* __restrict__ out)
{
    if (threadIdx.x == 0 && blockIdx.x == 0) {
        float s = 0.f;
        for (int i = 0; i < 16; i++) s += partb[i];
        out[0] = s * (1.f / 16.f);
    }
}

extern "C" void kernel_launch(void* const* d_in, const int* in_sizes, int n_in,
                              void* d_out, int out_size, void* d_ws, size_t ws_size,
                              hipStream_t stream)
{
    (void)in_sizes; (void)n_in; (void)out_size; (void)ws_size;
    const int*   char_ids    = (const int*)d_in[0];
    const int*   kb_word_ids = (const int*)d_in[1];
    const int*   word_begin  = (const int*)d_in[2];
    const int*   word_len    = (const int*)d_in[3];
    const int*   label       = (const int*)d_in[4];
    const int*   seqlen      = (const int*)d_in[5];
    const float* char_emb    = (const float*)d_in[6];
    const float* kb_emb      = (const float*)d_in[7];
    const float* dense_W     = (const float*)d_in[8];
    const float* dense_b     = (const float*)d_in[9];
    const float* crf_T       = (const float*)d_in[10];
    const float* f_Wcx = (const float*)d_in[11];
    const float* f_Wch = (const float*)d_in[12];
    const float* f_bc  = (const float*)d_in[13];
    const float* f_Wwx = (const float*)d_in[14];
    const float* f_Wwh = (const float*)d_in[15];
    const float* f_bw  = (const float*)d_in[16];
    const float* f_Wlx = (const float*)d_in[17];
    const float* f_Wlc = (const float*)d_in[18];
    const float* f_bl  = (const float*)d_in[19];
    const float* r_Wcx = (const float*)d_in[20];
    const float* r_Wch = (const float*)d_in[21];
    const float* r_bc  = (const float*)d_in[22];
    const float* r_Wwx = (const float*)d_in[23];
    const float* r_Wwh = (const float*)d_in[24];
    const float* r_bw  = (const float*)d_in[25];
    const float* r_Wlx = (const float*)d_in[26];
    const float* r_Wlc = (const float*)d_in[27];
    const float* r_bl  = (const float*)d_in[28];

    float* ws = (float*)d_ws;
    size_t o = 0;
    float* Xg     = ws + o; o += (size_t)2 * 2048 * 512;   // [dir][B*S][512]
    float* Xl     = ws + o; o += (size_t)2 * 2048 * 128;   // [dir][B*S][128]
    float* Wg     = ws + o; o += (size_t)2 * 1024 * 384;   // [dir][B*N][384]
    float* feats  = ws + o; o += (size_t)2048 * 256;       // [B*S][2H]
    float* logits = ws + o; o += (size_t)2048 * 32;
    float* partb  = ws + o; o += 16;

    gemm_char<<<dim3(256, 2), 256, 0, stream>>>(
        char_emb, char_ids, f_Wcx, r_Wcx, f_bc, r_bc,
        f_Wlx, r_Wlx, f_bl, r_bl, Xg, Xl);
    gemm_pair<128, 384, 8, 192><<<dim3(128, 2), 192, 0, stream>>>(
        kb_emb, kb_word_ids, f_Wwx, r_Wwx, f_bw, r_bw, Wg, 1024, 64, 0);

    lattice_kernel<<<32, 512, LAT_DYN_SMEM, stream>>>(
        Xg, Xl, Wg, f_Wch, r_Wch, f_Wwh, r_Wwh, f_Wlc, r_Wlc,
        word_begin, word_len, seqlen, feats);

    gemm_pair<256, 32, 16, 128><<<dim3(128, 1), 128, 0, stream>>>(
        feats, nullptr, dense_W, dense_W, dense_b, dense_b, logits, 2048, 128, 0);
    crf_kernel<<<8, 64, 0, stream>>>(logits, label, seqlen, crf_T, partb);
    finalize_kernel<<<1, 64, 0, stream>>>(partb, (float*)d_out);
}

// Round 11
// 463.466 us; speedup vs baseline: 1.1768x; 1.0710x over previous
//
#include <hip/hip_runtime.h>

// ---------------------------------------------------------------------------
// BiLstmCrf: bidirectional lattice-LSTM + CRF NLL -> one scalar. 3 launches:
//
//   1. gemm_pre : blocks x<256 = char path (Xg J=512 + Xl J=128 from one
//        staged char-emb gather); x>=256 = Wg path (kb_emb, J=384).
//        Also resets the CRF done-counter.
//   2. lattice_kernel : 32 WGs (one per (batch,dir)), 512 thr (8 waves).
//        Main loop UNCHANGED (proven 184 us): MFMA broadcast-A matvecs,
//        weights in VGPRs, h(f16)/c(f32) history in LDS, 1 lgkm barrier per
//        eventless step. NEW epilogue: computes this direction's PARTIAL
//        logits from the LDS h history (dense_W half staged as f16x2 into
//        the dead ch region, FDOT2), writing plog[dir] (256 KB) instead of
//        feats (2 MB). Bias folded into dir-0 partial.
//   3. crf_kernel : 8 blocks x 64 thr; lg = plogA + plogB; LDS-broadcast
//        alpha (proven form); finalize fused via atomic last-block counter.
// ---------------------------------------------------------------------------

typedef _Float16 f16x2 __attribute__((ext_vector_type(2)));
typedef _Float16 f16x8 __attribute__((ext_vector_type(8)));
typedef float    f32x4 __attribute__((ext_vector_type(4)));

__device__ __forceinline__ float sigm(float x) { return 1.f / (1.f + __expf(-x)); }
__device__ __forceinline__ float tanh_fast(float x) {
    return 1.f - 2.f / (__expf(2.f * x) + 1.f);
}
// lgkm-only barrier: LDS ops drained, vmem loads stay outstanding.
__device__ __forceinline__ void bar_lgkm() {
    asm volatile("s_waitcnt lgkmcnt(0)\n\ts_barrier" ::: "memory");
}

__device__ __forceinline__ f32x4 mfma16(f16x8 a, f16x8 b, f32x4 c) {
    return __builtin_amdgcn_mfma_f32_16x16x32_f16(a, b, c, 0, 0, 0);
}

#if defined(__has_builtin)
#if __has_builtin(__builtin_amdgcn_fdot2)
#define FDOT2(a, b, c) __builtin_amdgcn_fdot2((a), (b), (c), false)
#endif
#endif
#ifndef FDOT2
__device__ __forceinline__ float fdot2_sw(f16x2 a, f16x2 b, float c) {
    return fmaf((float)a.x, (float)b.x, fmaf((float)a.y, (float)b.y, c));
}
#define FDOT2(a, b, c) fdot2_sw((a), (b), (c))
#endif

// ---------------------------------------------------------------------------
// Combined pre-gemm. blockIdx.y = direction.
//   x in [0,256): char path — stage 8 rows of char_emb (rev for y=1),
//                 produce Xg (J=512) and Xl (J=128).
//   x in [256,384): Wg path — stage 8 rows of kb_emb, produce Wg (J=384,
//                 192 active compute threads).
// Block (0,0) thread 0 resets the CRF done-counter.
// ---------------------------------------------------------------------------
__global__ __launch_bounds__(256)
void gemm_pre(const float* __restrict__ cemb, const int* __restrict__ cidx,
              const float* __restrict__ kemb, const int* __restrict__ kidx,
              const float* __restrict__ Wg0, const float* __restrict__ Wg1,
              const float* __restrict__ bg0, const float* __restrict__ bg1,
              const float* __restrict__ Wl0, const float* __restrict__ Wl1,
              const float* __restrict__ bl0, const float* __restrict__ bl1,
              const float* __restrict__ Ww0, const float* __restrict__ Ww1,
              const float* __restrict__ bw0, const float* __restrict__ bw1,
              float* __restrict__ outg, float* __restrict__ outl,
              float* __restrict__ outw, int* __restrict__ done_cnt)
{
    constexpr int K = 128, RPB = 8, BLK = 256;
    const int y = blockIdx.y;
    const int tid = threadIdx.x;
    if (blockIdx.x == 0 && y == 0 && tid == 0) *done_cnt = 0;

    __shared__ __align__(16) float xs[RPB * K];
    __shared__ const float* srcs[RPB];

    if (blockIdx.x < 256) {
        // ================= char path =================
        const float* __restrict__ Wg = y ? Wg1 : Wg0;
        const float* __restrict__ bg = y ? bg1 : bg0;
        const float* __restrict__ Wl = y ? Wl1 : Wl0;
        const float* __restrict__ bl = y ? bl1 : bl0;
        float* __restrict__ og = outg + (size_t)y * 2048 * 512;
        float* __restrict__ ol = outl + (size_t)y * 2048 * 128;

        const int r0 = blockIdx.x * RPB;
        if (tid < RPB) {
            const int row = r0 + tid;
            const int bb = row >> 7, tt = row & 127;
            const int ts = y ? (127 - tt) : tt;
            srcs[tid] = cemb + (size_t)cidx[bb * 128 + ts] * K;
        }
        __syncthreads();
        constexpr int NQ = RPB * K / 4;
        for (int q = tid; q < NQ; q += BLK) {
            const int rr = q / (K / 4), qq = q - rr * (K / 4);
            ((float4*)xs)[q] = ((const float4*)srcs[rr])[qq];
        }
        __syncthreads();

        // phase 1: J = 512 (Xg)
        {
            constexpr int NJ4 = 128, RT = BLK / NJ4, RPT = RPB / RT;  // 2, 4
            const int jq = tid % NJ4;
            const int rg = tid / NJ4;
            float4 acc[RPT];
#pragma unroll
            for (int r = 0; r < RPT; ++r) acc[r] = make_float4(0.f, 0.f, 0.f, 0.f);
            const float4* __restrict__ W4 = (const float4*)Wg;
#pragma unroll 4
            for (int k = 0; k < K; ++k) {
                const float4 wv = W4[(size_t)k * NJ4 + jq];
#pragma unroll
                for (int r = 0; r < RPT; ++r) {
                    const float xv = xs[(rg * RPT + r) * K + k];
                    acc[r].x = fmaf(xv, wv.x, acc[r].x);
                    acc[r].y = fmaf(xv, wv.y, acc[r].y);
                    acc[r].z = fmaf(xv, wv.z, acc[r].z);
                    acc[r].w = fmaf(xv, wv.w, acc[r].w);
                }
            }
            const float4 bv = ((const float4*)bg)[jq];
#pragma unroll
            for (int r = 0; r < RPT; ++r) {
                const int row = r0 + rg * RPT + r;
                ((float4*)og)[(size_t)row * NJ4 + jq] =
                    make_float4(acc[r].x + bv.x, acc[r].y + bv.y,
                                acc[r].z + bv.z, acc[r].w + bv.w);
            }
        }
        // phase 2: J = 128 (Xl)
        {
            constexpr int NJ4 = 32;
            const int jq = tid % NJ4;
            const int rg = tid / NJ4;                                 // 0..7
            float4 acc = make_float4(0.f, 0.f, 0.f, 0.f);
            const float4* __restrict__ W4 = (const float4*)Wl;
#pragma unroll 4
            for (int k = 0; k < K; ++k) {
                const float4 wv = W4[(size_t)k * NJ4 + jq];
                const float xv = xs[rg * K + k];
                acc.x = fmaf(xv, wv.x, acc.x);
                acc.y = fmaf(xv, wv.y, acc.y);
                acc.z = fmaf(xv, wv.z, acc.z);
                acc.w = fmaf(xv, wv.w, acc.w);
            }
            const float4 bv = ((const float4*)bl)[jq];
            const int row = r0 + rg;
            ((float4*)ol)[(size_t)row * NJ4 + jq] =
                make_float4(acc.x + bv.x, acc.y + bv.y, acc.z + bv.z, acc.w + bv.w);
        }
    } else {
        // ================= Wg path (J = 384) =================
        const float* __restrict__ Ww = y ? Ww1 : Ww0;
        const float* __restrict__ bw = y ? bw1 : bw0;
        float* __restrict__ ow = outw + (size_t)y * 1024 * 384;

        const int r0 = (blockIdx.x - 256) * RPB;
        if (tid < RPB) {
            const int row = r0 + tid;
            const int bb = row >> 6, tt = row & 63;
            srcs[tid] = kemb + (size_t)kidx[bb * 64 + tt] * K;
        }
        __syncthreads();
        constexpr int NQ = RPB * K / 4;
        for (int q = tid; q < NQ; q += BLK) {
            const int rr = q / (K / 4), qq = q - rr * (K / 4);
            ((float4*)xs)[q] = ((const float4*)srcs[rr])[qq];
        }
        __syncthreads();

        constexpr int NJ4 = 96, RPT = 4;  // 192 active threads, 2 row-groups
        if (tid < 192) {
            const int jq = tid % NJ4;
            const int rg = tid / NJ4;
            float4 acc[RPT];
#pragma unroll
            for (int r = 0; r < RPT; ++r) acc[r] = make_float4(0.f, 0.f, 0.f, 0.f);
            const float4* __restrict__ W4 = (const float4*)Ww;
#pragma unroll 4
            for (int k = 0; k < K; ++k) {
                const float4 wv = W4[(size_t)k * NJ4 + jq];
#pragma unroll
                for (int r = 0; r < RPT; ++r) {
                    const float xv = xs[(rg * RPT + r) * K + k];
                    acc[r].x = fmaf(xv, wv.x, acc[r].x);
                    acc[r].y = fmaf(xv, wv.y, acc[r].y);
                    acc[r].z = fmaf(xv, wv.z, acc[r].z);
                    acc[r].w = fmaf(xv, wv.w, acc[r].w);
                }
            }
            const float4 bv = ((const float4*)bw)[jq];
#pragma unroll
            for (int r = 0; r < RPT; ++r) {
                const int row = r0 + rg * RPT + r;
                ((float4*)ow)[(size_t)row * NJ4 + jq] =
                    make_float4(acc[r].x + bv.x, acc[r].y + bv.y,
                                acc[r].z + bv.z, acc[r].w + bv.w);
            }
        }
    }
}

// ---------------------------------------------------------------------------
// Lattice scan. One WG per (batch,dir). MFMA layout: wave wid owns columns
// jm = 16*wid + (lane&15). Dynamic LDS: hh (f16, 129*128) + ch (f32, 129*128).
// Main loop UNCHANGED (proven 184 us). Epilogue: partial logits -> plog.
// ---------------------------------------------------------------------------
#define HH_BYTES (129 * 128 * 2)
#define CH_BYTES (129 * 128 * 4)
#define LAT_DYN_SMEM (HH_BYTES + CH_BYTES)

__global__ __launch_bounds__(512, 2)
void lattice_kernel(const float* __restrict__ Xg,    // [2][B*S][512]
                    const float* __restrict__ Xl,    // [2][B*S][128]
                    const float* __restrict__ Wgp,   // [2][B*N][384]
                    const float* __restrict__ Wch_f, const float* __restrict__ Wch_r,
                    const float* __restrict__ Wwh_f, const float* __restrict__ Wwh_r,
                    const float* __restrict__ Wlc_f, const float* __restrict__ Wlc_r,
                    const float* __restrict__ dense_W, const float* __restrict__ dense_b,
                    const int* __restrict__ word_begin, const int* __restrict__ word_len,
                    const int* __restrict__ seqlen,
                    float* __restrict__ plog)        // [2][B*S][32] partials
{
    extern __shared__ __align__(16) char dyn_smem[];
    _Float16* hh = (_Float16*)dyn_smem;                    // [129][128]
    float*    ch = (float*)(dyn_smem + HH_BYTES);          // [129][128]

    const int bdid = blockIdx.x;
    const int b = bdid >> 1, dir = bdid & 1;
    const int tid = threadIdx.x;
    const int wid = tid >> 6;     // wave 0..7
    const int ln  = tid & 63;     // lane
    const int lg  = ln >> 4;      // k-group 0..3 within MFMA operand
    const int jm  = wid * 16 + (ln & 15);   // owned column 0..127

    const float* Wch = dir ? Wch_r : Wch_f;
    const float* Wwh = dir ? Wwh_r : Wwh_f;
    const float* Wlc = dir ? Wlc_r : Wlc_f;

    // ---- weights -> VGPRs as MFMA B-fragments -----------------------------
    f16x8 Bc[4][4];   // [gate][kt]
#pragma unroll
    for (int g = 0; g < 4; ++g)
#pragma unroll
        for (int kt = 0; kt < 4; ++kt) {
            f16x8 v;
#pragma unroll
            for (int i = 0; i < 8; ++i)
                v[i] = (_Float16)Wch[(size_t)(kt * 32 + lg * 8 + i) * 512 + (g * 128 + jm)];
            Bc[g][kt] = v;
        }
    f16x8 Bw[3][4];   // [part][kt]
#pragma unroll
    for (int p = 0; p < 3; ++p)
#pragma unroll
        for (int kt = 0; kt < 4; ++kt) {
            f16x8 v;
#pragma unroll
            for (int i = 0; i < 8; ++i)
                v[i] = (_Float16)Wwh[(size_t)(kt * 32 + lg * 8 + i) * 384 + (p * 128 + jm)];
            Bw[p][kt] = v;
        }
    f16x8 Bl[4];      // [kt]
#pragma unroll
    for (int kt = 0; kt < 4; ++kt) {
        f16x8 v;
#pragma unroll
        for (int i = 0; i < 8; ++i)
            v[i] = (_Float16)Wlc[(size_t)(kt * 32 + lg * 8 + i) * 128 + jm];
        Bl[kt] = v;
    }

    // ---- static LDS --------------------------------------------------------
    __shared__ __align__(16) _Float16 cw2s[2][2][128];   // [chunk-parity][slot][col]
    __shared__ int ev_start[129];
    __shared__ int cnts[128];
    __shared__ int fills[128];
    __shared__ short ev_word[64];
    __shared__ short wbeg_s[64];

    const int sl = seqlen[b];

    // ---- event schedule ----------------------------------------------------
    if (tid < 128) { cnts[tid] = 0; fills[tid] = 0; }
    __syncthreads();
    int myvalid = 0, myed = 0;
    if (tid < 64) {
        const int bg = word_begin[b * 64 + tid];
        const int lnw = word_len[b * 64 + tid];
        int ef = bg + lnw; if (ef > 127) ef = 127;
        myvalid = (ef < sl);
        const int bd_ = dir ? (127 - ef) : bg;
        const int ed_ = dir ? (127 - bg) : ef;
        wbeg_s[tid] = (short)bd_;
        myed = ed_;
        if (myvalid) atomicAdd(&cnts[ed_], 1);
    }
    __syncthreads();
    if (tid == 0) {
        int run = 0; ev_start[0] = 0;
        for (int t = 0; t < 128; ++t) { run += cnts[t]; ev_start[t + 1] = run; }
    }
    __syncthreads();
    if (tid < 64 && myvalid) {
        const int pos = atomicAdd(&fills[myed], 1);
        ev_word[ev_start[myed] + pos] = (short)tid;
    }
    if (tid < 128) { hh[tid] = (_Float16)0.f; ch[tid] = 0.f; }   // slot 0
    __syncthreads();

    const float* Xg_b = Xg + ((size_t)dir * 2048 + (size_t)b * 128) * 512;
    const float* Xl_b = Xl + ((size_t)dir * 2048 + (size_t)b * 128) * 128;
    const float* Wg_b = Wgp + ((size_t)dir * 1024 + (size_t)b * 64) * 384;

    float h_reg = 0.f, c_reg = 0.f;

    // ---- pipeline registers: step-t event data prefetched at step t-1 ------
    int   curE, cur_ec0;
    int   cur_bgs[2] = {0, 0};
    float cur_wgp[2][3] = {};
    float xg_cur[4];
    {
        curE = ev_start[1];                // e0 = 0
        cur_ec0 = curE < 2 ? curE : 2;
#pragma unroll
        for (int s = 0; s < 2; ++s)
            if (s < cur_ec0) {
                const int wd = __builtin_amdgcn_readfirstlane((int)ev_word[s]);
                cur_bgs[s] = __builtin_amdgcn_readfirstlane((int)wbeg_s[wd]);
                const float* wgr = Wg_b + (size_t)wd * 384;
                cur_wgp[s][0] = wgr[jm];
                cur_wgp[s][1] = wgr[128 + jm];
                cur_wgp[s][2] = wgr[256 + jm];
            }
#pragma unroll
        for (int g = 0; g < 4; ++g) xg_cur[g] = Xg_b[g * 128 + jm];
    }

    for (int t = 0; t < 128; ++t) {
        // ---- A-fragments for char matvec: issue LDS reads first -----------
        f16x8 A[4];
#pragma unroll
        for (int kt = 0; kt < 4; ++kt)
            A[kt] = ((const f16x8*)hh)[t * 16 + kt * 4 + lg];

        // ---- Xl for current step (L2-resident; consumed after barrier) ----
        float xl = 0.f;
        if (curE > 0) xl = Xl_b[(size_t)t * 128 + jm];

        // ---- prefetch step t+1 (in flight across lgkm barriers) -----------
        int   nxtE = 0, nxt_ec0 = 0;
        int   nxt_bgs[2] = {0, 0};
        float nxt_wgp[2][3] = {};
        float xg_nxt[4] = {0.f, 0.f, 0.f, 0.f};
        if (t < 127) {
            const int e0n = ev_start[t + 1];
            nxtE = ev_start[t + 2] - e0n;
            nxt_ec0 = nxtE < 2 ? nxtE : 2;
#pragma unroll
            for (int s = 0; s < 2; ++s)
                if (s < nxt_ec0) {
                    const int wd = __builtin_amdgcn_readfirstlane((int)ev_word[e0n + s]);
                    nxt_bgs[s] = __builtin_amdgcn_readfirstlane((int)wbeg_s[wd]);
                    const float* wgr = Wg_b + (size_t)wd * 384;
                    nxt_wgp[s][0] = wgr[jm];
                    nxt_wgp[s][1] = wgr[128 + jm];
                    nxt_wgp[s][2] = wgr[256 + jm];
                }
#pragma unroll
            for (int g = 0; g < 4; ++g)
                xg_nxt[g] = Xg_b[(size_t)(t + 1) * 512 + g * 128 + jm];
        }

        // ---- char matvec: 16 MFMA, broadcast-A = h[t] ---------------------
        f32x4 d[4];
#pragma unroll
        for (int g = 0; g < 4; ++g) d[g] = (f32x4){0.f, 0.f, 0.f, 0.f};
#pragma unroll
        for (int kt = 0; kt < 4; ++kt)
#pragma unroll
            for (int g = 0; g < 4; ++g)
                d[g] = mfma16(A[kt], Bc[g][kt], d[g]);

        const float gi = sigm(d[0][0] + xg_cur[0]);
        const float gf = sigm(d[1][0] + xg_cur[1]);
        const float go = sigm(d[2][0] + xg_cur[2]);
        const float gg = tanh_fast(d[3][0] + xg_cur[3]);

        float accn = 0.f, accd = 0.f;
        if (curE > 0) {
            const int e0 = ev_start[t];
            // ---- first chunk (covers E<=2, the dominant case) -------------
            float cwreg[2] = {0.f, 0.f};
#pragma unroll
            for (int s = 0; s < 2; ++s)
                if (s < cur_ec0) {
                    f16x8 Ab[4];
#pragma unroll
                    for (int kt = 0; kt < 4; ++kt)
                        Ab[kt] = ((const f16x8*)hh)[cur_bgs[s] * 16 + kt * 4 + lg];
                    f32x4 ep[3];
#pragma unroll
                    for (int p = 0; p < 3; ++p) ep[p] = (f32x4){0.f, 0.f, 0.f, 0.f};
#pragma unroll
                    for (int kt = 0; kt < 4; ++kt)
#pragma unroll
                        for (int p = 0; p < 3; ++p)
                            ep[p] = mfma16(Ab[kt], Bw[p][kt], ep[p]);
                    const float wi = cur_wgp[s][0] + ep[0][0];
                    const float wf = cur_wgp[s][1] + ep[1][0];
                    const float wv = cur_wgp[s][2] + ep[2][0];
                    const float cb = ch[(size_t)cur_bgs[s] * 128 + jm];
                    const float cwv = sigm(wf) * cb + sigm(wi) * tanh_fast(wv);
                    cwreg[s] = cwv;
                    if (ln < 16) cw2s[0][s][jm] = (_Float16)cwv;
                }
            bar_lgkm();   // publish cw2s[0]
#pragma unroll
            for (int s = 0; s < 2; ++s)
                if (s < cur_ec0) {
                    f16x8 Ac[4];
#pragma unroll
                    for (int kt = 0; kt < 4; ++kt)
                        Ac[kt] = ((const f16x8*)(&cw2s[0][s][0]))[kt * 4 + lg];
                    f32x4 r = (f32x4){0.f, 0.f, 0.f, 0.f};
#pragma unroll
                    for (int kt = 0; kt < 4; ++kt)
                        r = mfma16(Ac[kt], Bl[kt], r);
                    const float lgv = sigm(xl + r[0]);
                    const float ew = __expf(lgv);
                    accn = fmaf(ew, cwreg[s], accn);
                    accd += ew;
                }
            // ---- rare tail: E > 2, simple sequential chunks ---------------
            for (int base2 = 2; base2 < curE; base2 += 2) {
                const int bb = (base2 >> 1) & 1;
                const int en = (curE - base2) < 2 ? (curE - base2) : 2;
                float cwr2[2] = {0.f, 0.f};
#pragma unroll
                for (int s = 0; s < 2; ++s)
                    if (s < en) {
                        const int wd = __builtin_amdgcn_readfirstlane((int)ev_word[e0 + base2 + s]);
                        const int bg2 = __builtin_amdgcn_readfirstlane((int)wbeg_s[wd]);
                        const float* wgr = Wg_b + (size_t)wd * 384;
                        const float wg0 = wgr[jm], wg1 = wgr[128 + jm], wg2 = wgr[256 + jm];
                        f16x8 Ab[4];
#pragma unroll
                        for (int kt = 0; kt < 4; ++kt)
                            Ab[kt] = ((const f16x8*)hh)[bg2 * 16 + kt * 4 + lg];
                        f32x4 ep[3];
#pragma unroll
                        for (int p = 0; p < 3; ++p) ep[p] = (f32x4){0.f, 0.f, 0.f, 0.f};
#pragma unroll
                        for (int kt = 0; kt < 4; ++kt)
#pragma unroll
                            for (int p = 0; p < 3; ++p)
                                ep[p] = mfma16(Ab[kt], Bw[p][kt], ep[p]);
                        const float wi = wg0 + ep[0][0];
                        const float wf = wg1 + ep[1][0];
                        const float wv = wg2 + ep[2][0];
                        const float cb = ch[(size_t)bg2 * 128 + jm];
                        const float cwv = sigm(wf) * cb + sigm(wi) * tanh_fast(wv);
                        cwr2[s] = cwv;
                        if (ln < 16) cw2s[bb][s][jm] = (_Float16)cwv;
                    }
                bar_lgkm();   // publish cw2s[bb]
#pragma unroll
                for (int s = 0; s < 2; ++s)
                    if (s < en) {
                        f16x8 Ac[4];
#pragma unroll
                        for (int kt = 0; kt < 4; ++kt)
                            Ac[kt] = ((const f16x8*)(&cw2s[bb][s][0]))[kt * 4 + lg];
                        f32x4 r = (f32x4){0.f, 0.f, 0.f, 0.f};
#pragma unroll
                        for (int kt = 0; kt < 4; ++kt)
                            r = mfma16(Ac[kt], Bl[kt], r);
                        const float lgv = sigm(xl + r[0]);
                        const float ew = __expf(lgv);
                        accn = fmaf(ew, cwr2[s], accn);
                        accd += ew;
                    }
            }
        }

        // ---- update (4 redundant lane-groups; group 0 writes) -------------
        float c_t;
        if (curE > 0) {
            const float ec = __expf(gi);
            c_t = (ec * gg + accn) / (ec + accd);
        } else {
            c_t = gf * c_reg + gi * gg;
        }
        const float h_t = go * tanh_fast(c_t);
        const bool v = dir ? (t >= 128 - sl) : (t < sl);
        const float hn = v ? h_t : h_reg;
        const float cn = v ? c_t : c_reg;
        h_reg = hn; c_reg = cn;
        if (ln < 16) {
            hh[(size_t)(t + 1) * 128 + jm] = (_Float16)hn;
            ch[(size_t)(t + 1) * 128 + jm] = cn;
        }

        // rotate pipeline
        curE = nxtE; cur_ec0 = nxt_ec0;
        cur_bgs[0] = nxt_bgs[0]; cur_bgs[1] = nxt_bgs[1];
#pragma unroll
        for (int s = 0; s < 2; ++s) {
            cur_wgp[s][0] = nxt_wgp[s][0];
            cur_wgp[s][1] = nxt_wgp[s][1];
            cur_wgp[s][2] = nxt_wgp[s][2];
        }
#pragma unroll
        for (int g = 0; g < 4; ++g) xg_cur[g] = xg_nxt[g];
        bar_lgkm();   // B: h/c (and cw2s buffers) visible for next step
    }

    // ---- epilogue: partial logits from LDS h history ----------------------
    // ch region is dead after the main loop (loop-end barrier passed by all
    // threads) — reuse it to stage this direction's dense_W half as f16x2:
    // Wd2[kk*32 + j] = (W[dir*128 + 2kk][j], W[dir*128 + 2kk+1][j]).
    {
        f16x2* Wd2 = (f16x2*)ch;
        for (int i = tid; i < 64 * 32; i += 512) {
            const int kk = i >> 5, j = i & 31;
            f16x2 v;
            v.x = (_Float16)dense_W[(size_t)(dir * 128 + 2 * kk) * 32 + j];
            v.y = (_Float16)dense_W[(size_t)(dir * 128 + 2 * kk + 1) * 32 + j];
            Wd2[i] = v;
        }
        bar_lgkm();
        const int j  = tid & 31;
        const int t0 = tid >> 5;  // 0..15
        const float bj = dir ? 0.f : dense_b[j];   // bias folded into dir-0
        for (int p = 0; p < 8; ++p) {
            const int t = p * 16 + t0;
            const bool v = dir ? (t >= 128 - sl) : (t < sl);
            float acc = bj;
            if (v) {
                const f16x2* hrow = (const f16x2*)(hh + (size_t)(t + 1) * 128);
#pragma unroll
                for (int kk = 0; kk < 64; ++kk)
                    acc = FDOT2(Wd2[kk * 32 + j], hrow[kk], acc);
            }
            const int s = dir ? (127 - t) : t;
            plog[((size_t)dir * 2048 + (size_t)b * 128 + s) * 32 + j] = acc;
        }
    }
}

// ---------------------------------------------------------------------------
// CRF: 2 batches per 64-thread block (one per 32-lane half). T columns in
// registers; alpha broadcast via LDS float4 (proven form). lg = plogA+plogB.
// Finalize fused: last block (atomic counter) reduces partb -> out.
// ---------------------------------------------------------------------------
__global__ void crf_kernel(const float* __restrict__ plog,   // [2][B*S][32]
                           const int* __restrict__ label,    // [B*S]
                           const int* __restrict__ seqlen,
                           const float* __restrict__ T,      // [32][32]
                           float* __restrict__ out_part,     // [16]
                           int* __restrict__ done_cnt,
                           float* __restrict__ out)          // scalar
{
    const int half = threadIdx.x >> 5;
    const int j    = threadIdx.x & 31;
    const int b    = blockIdx.x * 2 + half;

    float Tc[32];
#pragma unroll
    for (int i = 0; i < 32; ++i) Tc[i] = T[i * 32 + j];

    const float* lgA = plog + (size_t)b * 128 * 32;
    const float* lgB = plog + (size_t)2048 * 32 + (size_t)b * 128 * 32;
    const int* lab = label + b * 128;
    const int sl = seqlen[b];

    // gold score
    float g = 0.f;
#pragma unroll
    for (int r = 0; r < 4; ++r) {
        const int t = j + r * 32;
        if (t < sl) {
            g += lgA[t * 32 + lab[t]] + lgB[t * 32 + lab[t]];
            if (t >= 1) g += T[lab[t - 1] * 32 + lab[t]];
        }
    }
#pragma unroll
    for (int m = 16; m; m >>= 1) g += __shfl_xor(g, m, 32);

    __shared__ __align__(16) float alpha_s[2][32];
    float av = lgA[j] + lgB[j];
    alpha_s[half][j] = av;
    __syncthreads();
    for (int t = 1; t < 128; ++t) {
        float a[32];
        const float4* ap = (const float4*)alpha_s[half];
#pragma unroll
        for (int q = 0; q < 8; ++q) {
            const float4 v = ap[q];
            a[4 * q] = v.x; a[4 * q + 1] = v.y; a[4 * q + 2] = v.z; a[4 * q + 3] = v.w;
        }
        float m = -1e30f;
#pragma unroll
        for (int i = 0; i < 32; ++i) m = fmaxf(m, a[i] + Tc[i]);
        float s = 0.f;
#pragma unroll
        for (int i = 0; i < 32; ++i) s += __expf(a[i] + Tc[i] - m);
        float nv = m + __logf(s) + (lgA[t * 32 + j] + lgB[t * 32 + j]);
        if (t >= sl) nv = av;
        av = nv;
        __syncthreads();
        alpha_s[half][j] = av;
        __syncthreads();
    }
    // logZ over the half's 32 lanes
    float m2 = av;
#pragma unroll
    for (int m = 16; m; m >>= 1) m2 = fmaxf(m2, __shfl_xor(m2, m, 32));
    float s2 = __expf(av - m2);
#pragma unroll
    for (int m = 16; m; m >>= 1) s2 += __shfl_xor(s2, m, 32);
    if (j == 0) out_part[b] = (m2 + __logf(s2)) - g;

    // fused finalize: last block to arrive reduces
    __syncthreads();
    if (threadIdx.x == 0) {
        __threadfence();
        const int old = atomicAdd(done_cnt, 1);
        if (old == 7) {
            __threadfence();
            float s = 0.f;
            for (int i = 0; i < 16; ++i) s += out_part[i];
            out[0] = s * (1.f / 16.f);
        }
    }
}

extern "C" void kernel_launch(void* const* d_in, const int* in_sizes, int n_in,
                              void* d_out, int out_size, void* d_ws, size_t ws_size,
                              hipStream_t stream)
{
    (void)in_sizes; (void)n_in; (void)out_size; (void)ws_size;
    const int*   char_ids    = (const int*)d_in[0];
    const int*   kb_word_ids = (const int*)d_in[1];
    const int*   word_begin  = (const int*)d_in[2];
    const int*   word_len    = (const int*)d_in[3];
    const int*   label       = (const int*)d_in[4];
    const int*   seqlen      = (const int*)d_in[5];
    const float* char_emb    = (const float*)d_in[6];
    const float* kb_emb      = (const float*)d_in[7];
    const float* dense_W     = (const float*)d_in[8];
    const float* dense_b     = (const float*)d_in[9];
    const float* crf_T       = (const float*)d_in[10];
    const float* f_Wcx = (const float*)d_in[11];
    const float* f_Wch = (const float*)d_in[12];
    const float* f_bc  = (const float*)d_in[13];
    const float* f_Wwx = (const float*)d_in[14];
    const float* f_Wwh = (const float*)d_in[15];
    const float* f_bw  = (const float*)d_in[16];
    const float* f_Wlx = (const float*)d_in[17];
    const float* f_Wlc = (const float*)d_in[18];
    const float* f_bl  = (const float*)d_in[19];
    const float* r_Wcx = (const float*)d_in[20];
    const float* r_Wch = (const float*)d_in[21];
    const float* r_bc  = (const float*)d_in[22];
    const float* r_Wwx = (const float*)d_in[23];
    const float* r_Wwh = (const float*)d_in[24];
    const float* r_bw  = (const float*)d_in[25];
    const float* r_Wlx = (const float*)d_in[26];
    const float* r_Wlc = (const float*)d_in[27];
    const float* r_bl  = (const float*)d_in[28];

    float* ws = (float*)d_ws;
    size_t o = 0;
    float* Xg     = ws + o; o += (size_t)2 * 2048 * 512;   // [dir][B*S][512]
    float* Xl     = ws + o; o += (size_t)2 * 2048 * 128;   // [dir][B*S][128]
    float* Wg     = ws + o; o += (size_t)2 * 1024 * 384;   // [dir][B*N][384]
    float* plog   = ws + o; o += (size_t)2 * 2048 * 32;    // [dir][B*S][32]
    float* partb  = ws + o; o += 16;
    int*   dcnt   = (int*)(ws + o); o += 1;

    gemm_pre<<<dim3(384, 2), 256, 0, stream>>>(
        char_emb, char_ids, kb_emb, kb_word_ids,
        f_Wcx, r_Wcx, f_bc, r_bc,
        f_Wlx, r_Wlx, f_bl, r_bl,
        f_Wwx, r_Wwx, f_bw, r_bw,
        Xg, Xl, Wg, dcnt);

    lattice_kernel<<<32, 512, LAT_DYN_SMEM, stream>>>(
        Xg, Xl, Wg, f_Wch, r_Wch, f_Wwh, r_Wwh, f_Wlc, r_Wlc,
        dense_W, dense_b, word_begin, word_len, seqlen, plog);

    crf_kernel<<<8, 64, 0, stream>>>(plog, label, seqlen, crf_T,
                                     partb, dcnt, (float*)d_out);
}